// Round 15
// baseline (232.919 us; speedup 1.0000x reference)
//
#include <hip/hip_runtime.h>
#include <math.h>

#define NTOK 2048
#define DMODEL 1024
#define NHEAD 16
#define DHEAD 64
#define NTIL (NTOK / 64)      // 32 K-tiles total
#define CTIL (NTIL / 2)       // 16 K-tiles per pass-2 chunk

typedef _Float16 f16x8 __attribute__((ext_vector_type(8)));
typedef _Float16 f16x4 __attribute__((ext_vector_type(4)));
typedef _Float16 f16x2 __attribute__((ext_vector_type(2)));
typedef float f32x4 __attribute__((ext_vector_type(4)));
typedef float f32x16 __attribute__((ext_vector_type(16)));

union U32H2 { f16x2 h; unsigned u; };
union U8 { f16x8 v; unsigned u[4]; };

__device__ __forceinline__ void split16(float x, _Float16& hi, _Float16& lo) {
    hi = (_Float16)x;
    lo = (_Float16)(x - (float)hi);
}
__device__ __forceinline__ unsigned packh(_Float16 a, _Float16 b) {
    U32H2 c; c.h = f16x2{a, b}; return c.u;
}

// ---------- prep: W[k][n] f32 -> Wt_hi/Wt_lo [n][k] f16, 4 matrices ----------
__global__ void __launch_bounds__(256) prep_w_kernel(
        const float* __restrict__ Wq, const float* __restrict__ Wk,
        const float* __restrict__ Wv, const float* __restrict__ Wo,
        _Float16* __restrict__ Wt) {
    __shared__ float T[32][33];
    const int z = blockIdx.z;
    const float* W = (z == 0) ? Wq : (z == 1) ? Wk : (z == 2) ? Wv : Wo;
    _Float16* Whi = Wt + (size_t)z * 2 * 1024 * 1024;
    _Float16* Wlo = Whi + (size_t)1024 * 1024;
    const int t = threadIdx.x;
    const int k0 = blockIdx.y * 32, n0 = blockIdx.x * 32;
    const int r = t >> 3, c4 = (t & 7) * 4;
    const float4 v = *(const float4*)(W + (size_t)(k0 + r) * DMODEL + n0 + c4);
    T[r][c4 + 0] = v.x; T[r][c4 + 1] = v.y; T[r][c4 + 2] = v.z; T[r][c4 + 3] = v.w;
    __syncthreads();
    f16x4 hv, lv;
#pragma unroll
    for (int j = 0; j < 4; ++j) {
        _Float16 h, l;
        split16(T[c4 + j][r], h, l);
        hv[j] = h; lv[j] = l;
    }
    *(f16x4*)(Whi + (size_t)(n0 + r) * DMODEL + k0 + c4) = hv;
    *(f16x4*)(Wlo + (size_t)(n0 + r) * DMODEL + k0 + c4) = lv;
}

// ---------- prep: A (query/key/value) f32 -> hi/lo f16 planes ----------
__global__ void __launch_bounds__(256) prep_a_kernel(
        const float* __restrict__ q, const float* __restrict__ k, const float* __restrict__ v,
        _Float16* __restrict__ As) {   // layout: [z][hi/lo][2048*1024]
    const int z = blockIdx.y;
    const float* A = (z == 0) ? q : (z == 1) ? k : v;
    const size_t PL = (size_t)NTOK * DMODEL;
    _Float16* H = As + (size_t)z * 2 * PL;
    _Float16* L = H + PL;
    const size_t off = ((size_t)blockIdx.x * 256 + threadIdx.x) * 8;
    const float4 a = *(const float4*)(A + off);
    const float4 b = *(const float4*)(A + off + 4);
    f16x8 hv, lv; _Float16 h, lo;
    split16(a.x, h, lo); hv[0] = h; lv[0] = lo;
    split16(a.y, h, lo); hv[1] = h; lv[1] = lo;
    split16(a.z, h, lo); hv[2] = h; lv[2] = lo;
    split16(a.w, h, lo); hv[3] = h; lv[3] = lo;
    split16(b.x, h, lo); hv[4] = h; lv[4] = lo;
    split16(b.y, h, lo); hv[5] = h; lv[5] = lo;
    split16(b.z, h, lo); hv[6] = h; lv[6] = lo;
    split16(b.w, h, lo); hv[7] = h; lv[7] = lo;
    *(f16x8*)(H + off) = hv;
    *(f16x8*)(L + off) = lv;
}

// ---------- QKV projection: pre-split f16 MFMA GEMM, 64x128 tile, grid-balanced ----------
// Outputs: z=0 -> Qh+Ql (x0.125); z=1 -> Kh only; z=2 -> Vth only.
__global__ void __launch_bounds__(256) qkv_mfma_kernel(
        const _Float16* __restrict__ As,
        const _Float16* __restrict__ Wt,
        const float* __restrict__ bq, const float* __restrict__ bk, const float* __restrict__ bv,
        _Float16* __restrict__ Qh, _Float16* __restrict__ Ql,
        _Float16* __restrict__ Kh, _Float16* __restrict__ Vth) {
    __shared__ _Float16 Ah[64][40], Al[64][40], Bh[128][40], Bl[128][40];
    const int z = blockIdx.z;
    const size_t PL = (size_t)NTOK * DMODEL;
    const _Float16* AH = As + (size_t)z * 2 * PL;
    const _Float16* AL = AH + PL;
    const _Float16* WH = Wt + (size_t)z * 2 * 1024 * 1024;
    const _Float16* WL = WH + (size_t)1024 * 1024;
    const float* bias = (z == 0) ? bq : (z == 1) ? bk : bv;

    const int t = threadIdx.x;
    const int l = t & 63, wid = t >> 6;
    const int lr = l & 15, lk = l >> 4;
    const int m0 = blockIdx.y * 64, n0 = blockIdx.x * 128;
    const int wm = (wid >> 1) * 32, wn = (wid & 1) * 64;

    f32x4 acc[2][4];
#pragma unroll
    for (int mi = 0; mi < 2; ++mi)
#pragma unroll
        for (int ni = 0; ni < 4; ++ni)
#pragma unroll
            for (int e = 0; e < 4; ++e) acc[mi][ni][e] = 0.f;

    for (int k0 = 0; k0 < DMODEL; k0 += 32) {
        __syncthreads();
        {   // A: pre-split f16, 64x32 per plane
            const int r = t >> 2, c8 = (t & 3) * 8;
            *(f16x8*)&Ah[r][c8] = *(const f16x8*)(AH + (size_t)(m0 + r) * DMODEL + k0 + c8);
            *(f16x8*)&Al[r][c8] = *(const f16x8*)(AL + (size_t)(m0 + r) * DMODEL + k0 + c8);
        }
#pragma unroll
        for (int p = 0; p < 2; ++p) {   // B: 128x32 per plane
            const int idx = t + p * 256;
            const int r = idx >> 2, c8 = (idx & 3) * 8;
            *(f16x8*)&Bh[r][c8] = *(const f16x8*)(WH + (size_t)(n0 + r) * DMODEL + k0 + c8);
            *(f16x8*)&Bl[r][c8] = *(const f16x8*)(WL + (size_t)(n0 + r) * DMODEL + k0 + c8);
        }
        __syncthreads();

        f16x8 ah[2], al[2], bh[4], bl[4];
#pragma unroll
        for (int i = 0; i < 2; ++i) {
            ah[i] = *(f16x8*)&Ah[wm + i * 16 + lr][lk * 8];
            al[i] = *(f16x8*)&Al[wm + i * 16 + lr][lk * 8];
        }
#pragma unroll
        for (int i = 0; i < 4; ++i) {
            bh[i] = *(f16x8*)&Bh[wn + i * 16 + lr][lk * 8];
            bl[i] = *(f16x8*)&Bl[wn + i * 16 + lr][lk * 8];
        }
        __builtin_amdgcn_s_setprio(1);
#pragma unroll
        for (int mi = 0; mi < 2; ++mi)
#pragma unroll
            for (int ni = 0; ni < 4; ++ni) {
                acc[mi][ni] = __builtin_amdgcn_mfma_f32_16x16x32_f16(ah[mi], bh[ni], acc[mi][ni], 0, 0, 0);
                acc[mi][ni] = __builtin_amdgcn_mfma_f32_16x16x32_f16(ah[mi], bl[ni], acc[mi][ni], 0, 0, 0);
                acc[mi][ni] = __builtin_amdgcn_mfma_f32_16x16x32_f16(al[mi], bh[ni], acc[mi][ni], 0, 0, 0);
            }
        __builtin_amdgcn_s_setprio(0);
    }

#pragma unroll
    for (int ni = 0; ni < 4; ++ni) {
        const int col = n0 + wn + ni * 16 + lr;
        const float bv_ = bias[col];
#pragma unroll
        for (int mi = 0; mi < 2; ++mi) {
            if (z == 2) {
                f16x4 hv;
#pragma unroll
                for (int i = 0; i < 4; ++i) hv[i] = (_Float16)(acc[mi][ni][i] + bv_);
                const int row = m0 + wm + mi * 16 + lk * 4;
                *(f16x4*)(Vth + (size_t)col * NTOK + row) = hv;
            } else {
#pragma unroll
                for (int i = 0; i < 4; ++i) {
                    const int row = m0 + wm + mi * 16 + lk * 4 + i;
                    float v = acc[mi][ni][i] + bv_;
                    if (z == 0) {
                        v *= 0.125f;
                        _Float16 h, lo;
                        split16(v, h, lo);
                        Qh[(size_t)row * DMODEL + col] = h;
                        Ql[(size_t)row * DMODEL + col] = lo;
                    } else {
                        Kh[(size_t)row * DMODEL + col] = (_Float16)v;
                    }
                }
            }
        }
    }
}

// ---------- fused attention, K-chunked: pass1 full-l (duplicated per chunk), pass2 half-K ----------
// grid (16, 16, 2): x = q-block of 128 rows (4 waves x 32), y = head, z = K-half. 2 blocks/CU.
__global__ void __launch_bounds__(256, 2) fused_attn_kernel(
        const _Float16* __restrict__ Qh, const _Float16* __restrict__ Ql,
        const _Float16* __restrict__ Kh, const _Float16* __restrict__ Vth,
        float* __restrict__ attn, float* __restrict__ Xp0, float* __restrict__ Xp1) {
    __shared__ _Float16 KB[2][64][64];
    __shared__ _Float16 VB[2][64][64];
    const int t = threadIdx.x, l = t & 63, w = t >> 6, q = l & 31, h = l >> 5;
    const int hh = blockIdx.y, z = blockIdx.z;
    const int rw = blockIdx.x * 128 + w * 32;
    const int sr = t >> 3, sc = t & 7;
    const int qrow = rw + q;

    f16x8 qbh[4], qbl[4];
#pragma unroll
    for (int s = 0; s < 4; ++s) {
        const size_t off = (size_t)qrow * DMODEL + hh * DHEAD + s * 16 + h * 8;
        qbh[s] = *(const f16x8*)(Qh + off);
        qbl[s] = *(const f16x8*)(Ql + off);
    }

    auto stageK = [&](int buf, int j0) {
#pragma unroll
        for (int p = 0; p < 2; ++p) {
            const int r = sr + p * 32; const int cs = (sc ^ (r & 7)) * 8;
            *(f16x8*)&KB[buf][r][cs] = *(const f16x8*)(Kh + (size_t)(j0 + r) * DMODEL + hh * DHEAD + sc * 8);
        }
    };
    auto stageKV = [&](int buf, int j0) {
#pragma unroll
        for (int p = 0; p < 2; ++p) {
            const int r = sr + p * 32; const int cs = (sc ^ (r & 7)) * 8;
            *(f16x8*)&KB[buf][r][cs] = *(const f16x8*)(Kh + (size_t)(j0 + r) * DMODEL + hh * DHEAD + sc * 8);
            *(f16x8*)&VB[buf][r][cs] = *(const f16x8*)(Vth + (size_t)(hh * DHEAD + r) * NTOK + j0 + sc * 8);
        }
    };

    // ---- pass 1: full l = sum exp(s) over ALL K (identical in both chunks) ----
    float lsum = 0.f;
    stageK(0, 0);
    for (int it = 0; it < NTIL; ++it) {
        __syncthreads();
        const int cur = it & 1;
        if (it + 1 < NTIL) stageK(cur ^ 1, (it + 1) * 64);
#pragma unroll
        for (int kb = 0; kb < 2; ++kb) {
            f32x16 c;
#pragma unroll
            for (int r = 0; r < 16; ++r) c[r] = 0.f;
            __builtin_amdgcn_s_setprio(1);
#pragma unroll
            for (int s = 0; s < 4; ++s) {
                const int rk = kb * 32 + q; const int cc = ((2 * s + h) ^ (rk & 7)) * 8;
                const f16x8 ah = *(f16x8*)&KB[cur][rk][cc];
                c = __builtin_amdgcn_mfma_f32_32x32x16_f16(ah, qbh[s], c, 0, 0, 0);
                c = __builtin_amdgcn_mfma_f32_32x32x16_f16(ah, qbl[s], c, 0, 0, 0);
            }
            __builtin_amdgcn_s_setprio(0);
#pragma unroll
            for (int r = 0; r < 16; ++r) lsum += __expf(c[r]);
        }
    }
    lsum += __shfl_xor(lsum, 32);
    const float linv = 1.f / lsum;

    // ---- pass 2: this chunk's half of K — recompute s, write attn, PV ----
    f32x16 x0, x1;
#pragma unroll
    for (int r = 0; r < 16; ++r) { x0[r] = 0.f; x1[r] = 0.f; }

    const int jbase = z * CTIL * 64;
    __syncthreads();               // all pass-1 LDS reads complete
    stageKV(0, jbase);
    for (int it = 0; it < CTIL; ++it) {
        const int j0 = jbase + it * 64;
        __syncthreads();
        const int cur = it & 1;
        if (it + 1 < CTIL) stageKV(cur ^ 1, jbase + (it + 1) * 64);

#pragma unroll
        for (int kb = 0; kb < 2; ++kb) {
            f32x16 c;
#pragma unroll
            for (int r = 0; r < 16; ++r) c[r] = 0.f;
            __builtin_amdgcn_s_setprio(1);
#pragma unroll
            for (int s = 0; s < 4; ++s) {
                const int rk = kb * 32 + q; const int cc = ((2 * s + h) ^ (rk & 7)) * 8;
                const f16x8 ah = *(f16x8*)&KB[cur][rk][cc];
                c = __builtin_amdgcn_mfma_f32_32x32x16_f16(ah, qbh[s], c, 0, 0, 0);
                c = __builtin_amdgcn_mfma_f32_32x32x16_f16(ah, qbl[s], c, 0, 0, 0);
            }
            __builtin_amdgcn_s_setprio(0);

            float p[16];
#pragma unroll
            for (int r = 0; r < 16; ++r) p[r] = __expf(c[r]) * linv;

            const int kbase = j0 + kb * 32;
#pragma unroll
            for (int i = 0; i < 4; ++i) {
                f32x4 st;
                st[0] = p[4 * i]; st[1] = p[4 * i + 1]; st[2] = p[4 * i + 2]; st[3] = p[4 * i + 3];
                *(f32x4*)(attn + ((size_t)hh * NTOK + qrow) * NTOK + kbase + 8 * i + 4 * h) = st;
            }

            _Float16 hf[16];
#pragma unroll
            for (int r = 0; r < 16; ++r) hf[r] = (_Float16)p[r];
            unsigned ph[8];
#pragma unroll
            for (int i = 0; i < 8; ++i) ph[i] = packh(hf[2 * i], hf[2 * i + 1]);

#pragma unroll
            for (int ss = 0; ss < 2; ++ss) {
                const int b = 4 * ss;
                const unsigned eh0 = __shfl_xor(h ? ph[b + 0] : ph[b + 2], 32);
                const unsigned eh1 = __shfl_xor(h ? ph[b + 1] : ph[b + 3], 32);
                U8 pah;
                pah.u[0] = h ? eh0 : ph[b + 0]; pah.u[1] = h ? eh1 : ph[b + 1];
                pah.u[2] = h ? ph[b + 2] : eh0; pah.u[3] = h ? ph[b + 3] : eh1;
                const int ks = kb * 2 + ss;
                __builtin_amdgcn_s_setprio(1);
                {
                    const int rd0 = q; const int cv0 = ((2 * ks + h) ^ (rd0 & 7)) * 8;
                    const f16x8 vh = *(f16x8*)&VB[cur][rd0][cv0];
                    x0 = __builtin_amdgcn_mfma_f32_32x32x16_f16(pah.v, vh, x0, 0, 0, 0);
                }
                {
                    const int rd1 = 32 + q; const int cv1 = ((2 * ks + h) ^ (rd1 & 7)) * 8;
                    const f16x8 vh = *(f16x8*)&VB[cur][rd1][cv1];
                    x1 = __builtin_amdgcn_mfma_f32_32x32x16_f16(pah.v, vh, x1, 0, 0, 0);
                }
                __builtin_amdgcn_s_setprio(0);
            }
        }
    }

    float* __restrict__ Xout = z ? Xp1 : Xp0;
#pragma unroll
    for (int r = 0; r < 16; ++r) {
        const int qloc = (r & 3) + 8 * (r >> 2) + 4 * h;
        Xout[(size_t)(rw + qloc) * DMODEL + hh * DHEAD + q]      = x0[r];
        Xout[(size_t)(rw + qloc) * DMODEL + hh * DHEAD + 32 + q] = x1[r];
    }
}

// ---------- output projection: A = Xp0+Xp1 (f32) -> split, 64x128 tile ----------
__global__ void __launch_bounds__(256) out_mfma_kernel(
        const float* __restrict__ Xp0, const float* __restrict__ Xp1,
        const _Float16* __restrict__ WH, const _Float16* __restrict__ WL,
        const float* __restrict__ bo, float* __restrict__ out) {
    __shared__ _Float16 Ah[64][40], Al[64][40], Bh[128][40], Bl[128][40];
    const int t = threadIdx.x;
    const int l = t & 63, wid = t >> 6;
    const int lr = l & 15, lk = l >> 4;
    const int m0 = blockIdx.y * 64, n0 = blockIdx.x * 128;
    const int wm = (wid >> 1) * 32, wn = (wid & 1) * 64;

    f32x4 acc[2][4];
#pragma unroll
    for (int mi = 0; mi < 2; ++mi)
#pragma unroll
        for (int ni = 0; ni < 4; ++ni)
#pragma unroll
            for (int e = 0; e < 4; ++e) acc[mi][ni][e] = 0.f;

    for (int k0 = 0; k0 < DMODEL; k0 += 32) {
        __syncthreads();
#pragma unroll
        for (int p = 0; p < 2; ++p) {
            const int idx = t + p * 256;
            const int r = idx >> 3, c4 = (idx & 7) * 4;
            const size_t off = (size_t)(m0 + r) * DMODEL + k0 + c4;
            const float4 v0 = *(const float4*)(Xp0 + off);
            const float4 v1 = *(const float4*)(Xp1 + off);
            f16x4 hv, lv; _Float16 h, lo;
            split16(v0.x + v1.x, h, lo); hv[0] = h; lv[0] = lo;
            split16(v0.y + v1.y, h, lo); hv[1] = h; lv[1] = lo;
            split16(v0.z + v1.z, h, lo); hv[2] = h; lv[2] = lo;
            split16(v0.w + v1.w, h, lo); hv[3] = h; lv[3] = lo;
            *(f16x4*)&Ah[r][c4] = hv;
            *(f16x4*)&Al[r][c4] = lv;
        }
#pragma unroll
        for (int p = 0; p < 2; ++p) {
            const int idx = t + p * 256;
            const int r = idx >> 2, c8 = (idx & 3) * 8;
            *(f16x8*)&Bh[r][c8] = *(const f16x8*)(WH + (size_t)(n0 + r) * DMODEL + k0 + c8);
            *(f16x8*)&Bl[r][c8] = *(const f16x8*)(WL + (size_t)(n0 + r) * DMODEL + k0 + c8);
        }
        __syncthreads();

        f16x8 ah[2], al[2], bh[4], bl[4];
#pragma unroll
        for (int i = 0; i < 2; ++i) {
            ah[i] = *(f16x8*)&Ah[wm + i * 16 + lr][lk * 8];
            al[i] = *(f16x8*)&Al[wm + i * 16 + lr][lk * 8];
        }
#pragma unroll
        for (int i = 0; i < 4; ++i) {
            bh[i] = *(f16x8*)&Bh[wn + i * 16 + lr][lk * 8];
            bl[i] = *(f16x8*)&Bl[wn + i * 16 + lr][lk * 8];
        }
        __builtin_amdgcn_s_setprio(1);
#pragma unroll
        for (int mi = 0; mi < 2; ++mi)
#pragma unroll
            for (int ni = 0; ni < 4; ++ni) {
                acc[mi][ni] = __builtin_amdgcn_mfma_f32_16x16x32_f16(ah[mi], bh[ni], acc[mi][ni], 0, 0, 0);
                acc[mi][ni] = __builtin_amdgcn_mfma_f32_16x16x32_f16(ah[mi], bl[ni], acc[mi][ni], 0, 0, 0);
                acc[mi][ni] = __builtin_amdgcn_mfma_f32_16x16x32_f16(al[mi], bh[ni], acc[mi][ni], 0, 0, 0);
            }
        __builtin_amdgcn_s_setprio(0);
    }

#pragma unroll
    for (int ni = 0; ni < 4; ++ni) {
        const int col = n0 + wn + ni * 16 + lr;
        const float bv_ = bo[col];
#pragma unroll
        for (int mi = 0; mi < 2; ++mi)
#pragma unroll
            for (int i = 0; i < 4; ++i) {
                const int row = m0 + wm + mi * 16 + lk * 4 + i;
                out[(size_t)row * DMODEL + col] = acc[mi][ni][i] + bv_;
            }
    }
}

extern "C" void kernel_launch(void* const* d_in, const int* in_sizes, int n_in,
                              void* d_out, int out_size, void* d_ws, size_t ws_size,
                              hipStream_t stream) {
    (void)in_sizes; (void)n_in; (void)out_size; (void)ws_size;
    const float* query = (const float*)d_in[0];
    const float* key_  = (const float*)d_in[1];
    const float* value = (const float*)d_in[2];
    const float* Wq = (const float*)d_in[3];
    const float* bq = (const float*)d_in[4];
    const float* Wk = (const float*)d_in[5];
    const float* bk = (const float*)d_in[6];
    const float* Wv = (const float*)d_in[7];
    const float* bv = (const float*)d_in[8];
    const float* Wo = (const float*)d_in[9];
    const float* bo = (const float*)d_in[10];

    float* out  = (float*)d_out;
    float* attn = out + (size_t)NTOK * DMODEL;

    const size_t MM = (size_t)1024 * 1024;
    _Float16* ws16 = (_Float16*)d_ws;          // 48 MB used
    _Float16* Wt  = ws16;                      // 8 planes (Wq,Wk,Wv,Wo x hi/lo), 16 MB
    _Float16* Qh  = ws16 + 8 * MM;             // 4 x 4 MB planes
    _Float16* Ql  = Qh  + 2 * MM;
    _Float16* Kh_ = Ql  + 2 * MM;
    _Float16* Vth = Kh_ + 2 * MM;

    // dead-after-qkv alias: Xp0 (8 MB) over Wq/Wk hi planes; Xp1 fresh at 40 MB offset
    float* Xp0 = (float*)ws16;
    float* Xp1 = (float*)(ws16 + 20 * MM);

    // A-split scratch lives in the attn output region (dead until fused_attn rewrites it)
    _Float16* As = (_Float16*)attn;            // 12 MB of 268 MB

    dim3 blk(256);
    prep_w_kernel<<<dim3(32, 32, 4), blk, 0, stream>>>(Wq, Wk, Wv, Wo, Wt);
    prep_a_kernel<<<dim3(1024, 3), blk, 0, stream>>>(query, key_, value, As);
    qkv_mfma_kernel<<<dim3(8, 32, 3), blk, 0, stream>>>(As, Wt, bq, bk, bv,
                                                        Qh, Ql, Kh_, Vth);
    fused_attn_kernel<<<dim3(16, 16, 2), blk, 0, stream>>>(Qh, Ql, Kh_, Vth, attn, Xp0, Xp1);
    out_mfma_kernel<<<dim3(8, 32), blk, 0, stream>>>(Xp0, Xp1, Wt + 6 * MM, Wt + 7 * MM, bo, out);
}

// Round 16
// 217.775 us; speedup vs baseline: 1.0695x; 1.0695x over previous
//
#include <hip/hip_runtime.h>
#include <math.h>

#define NTOK 2048
#define DMODEL 1024
#define NHEAD 16
#define DHEAD 64
#define NTIL (NTOK / 64)   // 32 K-tiles

typedef _Float16 f16x8 __attribute__((ext_vector_type(8)));
typedef _Float16 f16x4 __attribute__((ext_vector_type(4)));
typedef _Float16 f16x2 __attribute__((ext_vector_type(2)));
typedef float f32x4 __attribute__((ext_vector_type(4)));
typedef float f32x16 __attribute__((ext_vector_type(16)));

union U32H2 { f16x2 h; unsigned u; };
union U8 { f16x8 v; unsigned u[4]; };

__device__ __forceinline__ void split16(float x, _Float16& hi, _Float16& lo) {
    hi = (_Float16)x;
    lo = (_Float16)(x - (float)hi);
}
__device__ __forceinline__ unsigned packh(_Float16 a, _Float16 b) {
    U32H2 c; c.h = f16x2{a, b}; return c.u;
}

// ---------- prep: W[k][n] f32 -> Wt_hi/Wt_lo [n][k] f16, 4 matrices ----------
__global__ void __launch_bounds__(256) prep_w_kernel(
        const float* __restrict__ Wq, const float* __restrict__ Wk,
        const float* __restrict__ Wv, const float* __restrict__ Wo,
        _Float16* __restrict__ Wt) {
    __shared__ float T[32][33];
    const int z = blockIdx.z;
    const float* W = (z == 0) ? Wq : (z == 1) ? Wk : (z == 2) ? Wv : Wo;
    _Float16* Whi = Wt + (size_t)z * 2 * 1024 * 1024;
    _Float16* Wlo = Whi + (size_t)1024 * 1024;
    const int t = threadIdx.x;
    const int k0 = blockIdx.y * 32, n0 = blockIdx.x * 32;
    const int r = t >> 3, c4 = (t & 7) * 4;
    const float4 v = *(const float4*)(W + (size_t)(k0 + r) * DMODEL + n0 + c4);
    T[r][c4 + 0] = v.x; T[r][c4 + 1] = v.y; T[r][c4 + 2] = v.z; T[r][c4 + 3] = v.w;
    __syncthreads();
    f16x4 hv, lv;
#pragma unroll
    for (int j = 0; j < 4; ++j) {
        _Float16 h, l;
        split16(T[c4 + j][r], h, l);
        hv[j] = h; lv[j] = l;
    }
    *(f16x4*)(Whi + (size_t)(n0 + r) * DMODEL + k0 + c4) = hv;
    *(f16x4*)(Wlo + (size_t)(n0 + r) * DMODEL + k0 + c4) = lv;
}

// ---------- prep: A (query/key/value) f32 -> hi/lo f16 planes ----------
__global__ void __launch_bounds__(256) prep_a_kernel(
        const float* __restrict__ q, const float* __restrict__ k, const float* __restrict__ v,
        _Float16* __restrict__ As) {   // layout: [z][hi/lo][2048*1024]
    const int z = blockIdx.y;
    const float* A = (z == 0) ? q : (z == 1) ? k : v;
    const size_t PL = (size_t)NTOK * DMODEL;
    _Float16* H = As + (size_t)z * 2 * PL;
    _Float16* L = H + PL;
    const size_t off = ((size_t)blockIdx.x * 256 + threadIdx.x) * 8;
    const float4 a = *(const float4*)(A + off);
    const float4 b = *(const float4*)(A + off + 4);
    f16x8 hv, lv; _Float16 h, lo;
    split16(a.x, h, lo); hv[0] = h; lv[0] = lo;
    split16(a.y, h, lo); hv[1] = h; lv[1] = lo;
    split16(a.z, h, lo); hv[2] = h; lv[2] = lo;
    split16(a.w, h, lo); hv[3] = h; lv[3] = lo;
    split16(b.x, h, lo); hv[4] = h; lv[4] = lo;
    split16(b.y, h, lo); hv[5] = h; lv[5] = lo;
    split16(b.z, h, lo); hv[6] = h; lv[6] = lo;
    split16(b.w, h, lo); hv[7] = h; lv[7] = lo;
    *(f16x8*)(H + off) = hv;
    *(f16x8*)(L + off) = lv;
}

// ---------- QKV projection: pre-split f16 MFMA GEMM, 64x128 tile, grid-balanced ----------
// Outputs: z=0 -> Qh+Ql (x0.125); z=1 -> Kh only; z=2 -> Vth only.
__global__ void __launch_bounds__(256) qkv_mfma_kernel(
        const _Float16* __restrict__ As,
        const _Float16* __restrict__ Wt,
        const float* __restrict__ bq, const float* __restrict__ bk, const float* __restrict__ bv,
        _Float16* __restrict__ Qh, _Float16* __restrict__ Ql,
        _Float16* __restrict__ Kh, _Float16* __restrict__ Vth) {
    __shared__ _Float16 Ah[64][40], Al[64][40], Bh[128][40], Bl[128][40];
    const int z = blockIdx.z;
    const size_t PL = (size_t)NTOK * DMODEL;
    const _Float16* AH = As + (size_t)z * 2 * PL;
    const _Float16* AL = AH + PL;
    const _Float16* WH = Wt + (size_t)z * 2 * 1024 * 1024;
    const _Float16* WL = WH + (size_t)1024 * 1024;
    const float* bias = (z == 0) ? bq : (z == 1) ? bk : bv;

    const int t = threadIdx.x;
    const int l = t & 63, wid = t >> 6;
    const int lr = l & 15, lk = l >> 4;
    const int m0 = blockIdx.y * 64, n0 = blockIdx.x * 128;
    const int wm = (wid >> 1) * 32, wn = (wid & 1) * 64;

    f32x4 acc[2][4];
#pragma unroll
    for (int mi = 0; mi < 2; ++mi)
#pragma unroll
        for (int ni = 0; ni < 4; ++ni)
#pragma unroll
            for (int e = 0; e < 4; ++e) acc[mi][ni][e] = 0.f;

    for (int k0 = 0; k0 < DMODEL; k0 += 32) {
        __syncthreads();
        {   // A: pre-split f16, 64x32 per plane
            const int r = t >> 2, c8 = (t & 3) * 8;
            *(f16x8*)&Ah[r][c8] = *(const f16x8*)(AH + (size_t)(m0 + r) * DMODEL + k0 + c8);
            *(f16x8*)&Al[r][c8] = *(const f16x8*)(AL + (size_t)(m0 + r) * DMODEL + k0 + c8);
        }
#pragma unroll
        for (int p = 0; p < 2; ++p) {   // B: 128x32 per plane
            const int idx = t + p * 256;
            const int r = idx >> 2, c8 = (idx & 3) * 8;
            *(f16x8*)&Bh[r][c8] = *(const f16x8*)(WH + (size_t)(n0 + r) * DMODEL + k0 + c8);
            *(f16x8*)&Bl[r][c8] = *(const f16x8*)(WL + (size_t)(n0 + r) * DMODEL + k0 + c8);
        }
        __syncthreads();

        f16x8 ah[2], al[2], bh[4], bl[4];
#pragma unroll
        for (int i = 0; i < 2; ++i) {
            ah[i] = *(f16x8*)&Ah[wm + i * 16 + lr][lk * 8];
            al[i] = *(f16x8*)&Al[wm + i * 16 + lr][lk * 8];
        }
#pragma unroll
        for (int i = 0; i < 4; ++i) {
            bh[i] = *(f16x8*)&Bh[wn + i * 16 + lr][lk * 8];
            bl[i] = *(f16x8*)&Bl[wn + i * 16 + lr][lk * 8];
        }
        __builtin_amdgcn_s_setprio(1);
#pragma unroll
        for (int mi = 0; mi < 2; ++mi)
#pragma unroll
            for (int ni = 0; ni < 4; ++ni) {
                acc[mi][ni] = __builtin_amdgcn_mfma_f32_16x16x32_f16(ah[mi], bh[ni], acc[mi][ni], 0, 0, 0);
                acc[mi][ni] = __builtin_amdgcn_mfma_f32_16x16x32_f16(ah[mi], bl[ni], acc[mi][ni], 0, 0, 0);
                acc[mi][ni] = __builtin_amdgcn_mfma_f32_16x16x32_f16(al[mi], bh[ni], acc[mi][ni], 0, 0, 0);
            }
        __builtin_amdgcn_s_setprio(0);
    }

#pragma unroll
    for (int ni = 0; ni < 4; ++ni) {
        const int col = n0 + wn + ni * 16 + lr;
        const float bv_ = bias[col];
#pragma unroll
        for (int mi = 0; mi < 2; ++mi) {
            if (z == 2) {
                f16x4 hv;
#pragma unroll
                for (int i = 0; i < 4; ++i) hv[i] = (_Float16)(acc[mi][ni][i] + bv_);
                const int row = m0 + wm + mi * 16 + lk * 4;
                *(f16x4*)(Vth + (size_t)col * NTOK + row) = hv;
            } else {
#pragma unroll
                for (int i = 0; i < 4; ++i) {
                    const int row = m0 + wm + mi * 16 + lk * 4 + i;
                    float v = acc[mi][ni][i] + bv_;
                    if (z == 0) {
                        v *= 0.125f;
                        _Float16 h, lo;
                        split16(v, h, lo);
                        Qh[(size_t)row * DMODEL + col] = h;
                        Ql[(size_t)row * DMODEL + col] = lo;
                    } else {
                        Kh[(size_t)row * DMODEL + col] = (_Float16)v;
                    }
                }
            }
        }
    }
}

// ---------- fused attention: 4-deep LDS pipeline, barrier per 2 tiles ----------
// grid (16, 16): x = q-block of 128 rows (4 waves x 32), y = head.
__global__ void __launch_bounds__(256, 2) fused_attn_kernel(
        const _Float16* __restrict__ Qh, const _Float16* __restrict__ Ql,
        const _Float16* __restrict__ Kh, const _Float16* __restrict__ Vth,
        float* __restrict__ attn, float* __restrict__ Xp) {
    __shared__ _Float16 KB[4][64][64];
    __shared__ _Float16 VB[4][64][64];
    const int t = threadIdx.x, l = t & 63, w = t >> 6, q = l & 31, h = l >> 5;
    const int hh = blockIdx.y;
    const int rw = blockIdx.x * 128 + w * 32;
    const int sr = t >> 3, sc = t & 7;
    const int qrow = rw + q;

    f16x8 qbh[4], qbl[4];
#pragma unroll
    for (int s = 0; s < 4; ++s) {
        const size_t off = (size_t)qrow * DMODEL + hh * DHEAD + s * 16 + h * 8;
        qbh[s] = *(const f16x8*)(Qh + off);
        qbl[s] = *(const f16x8*)(Ql + off);
    }

    auto stageK = [&](int buf, int j0) {
#pragma unroll
        for (int p = 0; p < 2; ++p) {
            const int r = sr + p * 32; const int cs = (sc ^ (r & 7)) * 8;
            *(f16x8*)&KB[buf][r][cs] = *(const f16x8*)(Kh + (size_t)(j0 + r) * DMODEL + hh * DHEAD + sc * 8);
        }
    };
    auto stageV = [&](int buf, int j0) {
#pragma unroll
        for (int p = 0; p < 2; ++p) {
            const int r = sr + p * 32; const int cs = (sc ^ (r & 7)) * 8;
            *(f16x8*)&VB[buf][r][cs] = *(const f16x8*)(Vth + (size_t)(hh * DHEAD + r) * NTOK + j0 + sc * 8);
        }
    };

    // QK^T for one tile in buffer `buf` -> c[2][16]
    auto qkt = [&](int buf, f32x16 (&c)[2]) {
#pragma unroll
        for (int kb = 0; kb < 2; ++kb) {
#pragma unroll
            for (int r = 0; r < 16; ++r) c[kb][r] = 0.f;
            __builtin_amdgcn_s_setprio(1);
#pragma unroll
            for (int s = 0; s < 4; ++s) {
                const int rk = kb * 32 + q; const int cc = ((2 * s + h) ^ (rk & 7)) * 8;
                const f16x8 ah = *(f16x8*)&KB[buf][rk][cc];
                c[kb] = __builtin_amdgcn_mfma_f32_32x32x16_f16(ah, qbh[s], c[kb], 0, 0, 0);
                c[kb] = __builtin_amdgcn_mfma_f32_32x32x16_f16(ah, qbl[s], c[kb], 0, 0, 0);
            }
            __builtin_amdgcn_s_setprio(0);
        }
    };

    // ---- pass 1: l = sum exp(s), 4-deep K pipeline, barrier/2 tiles ----
    float lsum = 0.f;
    stageK(0, 0);
    stageK(1, 64);
    for (int it = 0; it < NTIL; it += 2) {
        __syncthreads();
        if (it + 2 < NTIL) stageK((it + 2) & 3, (it + 2) * 64);
        if (it + 3 < NTIL) stageK((it + 3) & 3, (it + 3) * 64);
#pragma unroll
        for (int u = 0; u < 2; ++u) {
            f32x16 c[2];
            qkt((it + u) & 3, c);
#pragma unroll
            for (int kb = 0; kb < 2; ++kb)
#pragma unroll
                for (int r = 0; r < 16; ++r) lsum += __expf(c[kb][r]);
        }
    }
    lsum += __shfl_xor(lsum, 32);
    const float linv = 1.f / lsum;

    // ---- pass 2: recompute s, write attn, PV; 4-deep K+V pipeline ----
    f32x16 x0, x1;
#pragma unroll
    for (int r = 0; r < 16; ++r) { x0[r] = 0.f; x1[r] = 0.f; }

    __syncthreads();               // all pass-1 LDS reads complete
    stageK(0, 0);  stageV(0, 0);
    stageK(1, 64); stageV(1, 64);
    for (int it = 0; it < NTIL; it += 2) {
        __syncthreads();
        if (it + 2 < NTIL) { stageK((it + 2) & 3, (it + 2) * 64); stageV((it + 2) & 3, (it + 2) * 64); }
        if (it + 3 < NTIL) { stageK((it + 3) & 3, (it + 3) * 64); stageV((it + 3) & 3, (it + 3) * 64); }
#pragma unroll
        for (int u = 0; u < 2; ++u) {
            const int cur = (it + u) & 3;
            const int j0 = (it + u) * 64;
            f32x16 c[2];
            qkt(cur, c);

#pragma unroll
            for (int kb = 0; kb < 2; ++kb) {
                float p[16];
#pragma unroll
                for (int r = 0; r < 16; ++r) p[r] = __expf(c[kb][r]) * linv;

                const int kbase = j0 + kb * 32;
#pragma unroll
                for (int i = 0; i < 4; ++i) {
                    f32x4 st;
                    st[0] = p[4 * i]; st[1] = p[4 * i + 1]; st[2] = p[4 * i + 2]; st[3] = p[4 * i + 3];
                    *(f32x4*)(attn + ((size_t)hh * NTOK + qrow) * NTOK + kbase + 8 * i + 4 * h) = st;
                }

                _Float16 hf[16];
#pragma unroll
                for (int r = 0; r < 16; ++r) hf[r] = (_Float16)p[r];
                unsigned ph[8];
#pragma unroll
                for (int i = 0; i < 8; ++i) ph[i] = packh(hf[2 * i], hf[2 * i + 1]);

#pragma unroll
                for (int ss = 0; ss < 2; ++ss) {
                    const int b = 4 * ss;
                    const unsigned eh0 = __shfl_xor(h ? ph[b + 0] : ph[b + 2], 32);
                    const unsigned eh1 = __shfl_xor(h ? ph[b + 1] : ph[b + 3], 32);
                    U8 pah;
                    pah.u[0] = h ? eh0 : ph[b + 0]; pah.u[1] = h ? eh1 : ph[b + 1];
                    pah.u[2] = h ? ph[b + 2] : eh0; pah.u[3] = h ? ph[b + 3] : eh1;
                    const int ks = kb * 2 + ss;
                    __builtin_amdgcn_s_setprio(1);
                    {
                        const int rd0 = q; const int cv0 = ((2 * ks + h) ^ (rd0 & 7)) * 8;
                        const f16x8 vh = *(f16x8*)&VB[cur][rd0][cv0];
                        x0 = __builtin_amdgcn_mfma_f32_32x32x16_f16(pah.v, vh, x0, 0, 0, 0);
                    }
                    {
                        const int rd1 = 32 + q; const int cv1 = ((2 * ks + h) ^ (rd1 & 7)) * 8;
                        const f16x8 vh = *(f16x8*)&VB[cur][rd1][cv1];
                        x1 = __builtin_amdgcn_mfma_f32_32x32x16_f16(pah.v, vh, x1, 0, 0, 0);
                    }
                    __builtin_amdgcn_s_setprio(0);
                }
            }
        }
    }

#pragma unroll
    for (int r = 0; r < 16; ++r) {
        const int qloc = (r & 3) + 8 * (r >> 2) + 4 * h;
        Xp[(size_t)(rw + qloc) * DMODEL + hh * DHEAD + q]      = x0[r];
        Xp[(size_t)(rw + qloc) * DMODEL + hh * DHEAD + 32 + q] = x1[r];
    }
}

// ---------- output projection: A = Xp (f32) -> split, 64x128 tile ----------
__global__ void __launch_bounds__(256) out_mfma_kernel(
        const float* __restrict__ Xp,
        const _Float16* __restrict__ WH, const _Float16* __restrict__ WL,
        const float* __restrict__ bo, float* __restrict__ out) {
    __shared__ _Float16 Ah[64][40], Al[64][40], Bh[128][40], Bl[128][40];
    const int t = threadIdx.x;
    const int l = t & 63, wid = t >> 6;
    const int lr = l & 15, lk = l >> 4;
    const int m0 = blockIdx.y * 64, n0 = blockIdx.x * 128;
    const int wm = (wid >> 1) * 32, wn = (wid & 1) * 64;

    f32x4 acc[2][4];
#pragma unroll
    for (int mi = 0; mi < 2; ++mi)
#pragma unroll
        for (int ni = 0; ni < 4; ++ni)
#pragma unroll
            for (int e = 0; e < 4; ++e) acc[mi][ni][e] = 0.f;

    for (int k0 = 0; k0 < DMODEL; k0 += 32) {
        __syncthreads();
#pragma unroll
        for (int p = 0; p < 2; ++p) {
            const int idx = t + p * 256;
            const int r = idx >> 3, c4 = (idx & 7) * 4;
            const size_t off = (size_t)(m0 + r) * DMODEL + k0 + c4;
            const float4 v0 = *(const float4*)(Xp + off);
            f16x4 hv, lv; _Float16 h, lo;
            split16(v0.x, h, lo); hv[0] = h; lv[0] = lo;
            split16(v0.y, h, lo); hv[1] = h; lv[1] = lo;
            split16(v0.z, h, lo); hv[2] = h; lv[2] = lo;
            split16(v0.w, h, lo); hv[3] = h; lv[3] = lo;
            *(f16x4*)&Ah[r][c4] = hv;
            *(f16x4*)&Al[r][c4] = lv;
        }
#pragma unroll
        for (int p = 0; p < 2; ++p) {
            const int idx = t + p * 256;
            const int r = idx >> 2, c8 = (idx & 3) * 8;
            *(f16x8*)&Bh[r][c8] = *(const f16x8*)(WH + (size_t)(n0 + r) * DMODEL + k0 + c8);
            *(f16x8*)&Bl[r][c8] = *(const f16x8*)(WL + (size_t)(n0 + r) * DMODEL + k0 + c8);
        }
        __syncthreads();

        f16x8 ah[2], al[2], bh[4], bl[4];
#pragma unroll
        for (int i = 0; i < 2; ++i) {
            ah[i] = *(f16x8*)&Ah[wm + i * 16 + lr][lk * 8];
            al[i] = *(f16x8*)&Al[wm + i * 16 + lr][lk * 8];
        }
#pragma unroll
        for (int i = 0; i < 4; ++i) {
            bh[i] = *(f16x8*)&Bh[wn + i * 16 + lr][lk * 8];
            bl[i] = *(f16x8*)&Bl[wn + i * 16 + lr][lk * 8];
        }
        __builtin_amdgcn_s_setprio(1);
#pragma unroll
        for (int mi = 0; mi < 2; ++mi)
#pragma unroll
            for (int ni = 0; ni < 4; ++ni) {
                acc[mi][ni] = __builtin_amdgcn_mfma_f32_16x16x32_f16(ah[mi], bh[ni], acc[mi][ni], 0, 0, 0);
                acc[mi][ni] = __builtin_amdgcn_mfma_f32_16x16x32_f16(ah[mi], bl[ni], acc[mi][ni], 0, 0, 0);
                acc[mi][ni] = __builtin_amdgcn_mfma_f32_16x16x32_f16(al[mi], bh[ni], acc[mi][ni], 0, 0, 0);
            }
        __builtin_amdgcn_s_setprio(0);
    }

#pragma unroll
    for (int ni = 0; ni < 4; ++ni) {
        const int col = n0 + wn + ni * 16 + lr;
        const float bv_ = bo[col];
#pragma unroll
        for (int mi = 0; mi < 2; ++mi)
#pragma unroll
            for (int i = 0; i < 4; ++i) {
                const int row = m0 + wm + mi * 16 + lk * 4 + i;
                out[(size_t)row * DMODEL + col] = acc[mi][ni][i] + bv_;
            }
    }
}

extern "C" void kernel_launch(void* const* d_in, const int* in_sizes, int n_in,
                              void* d_out, int out_size, void* d_ws, size_t ws_size,
                              hipStream_t stream) {
    (void)in_sizes; (void)n_in; (void)out_size; (void)ws_size;
    const float* query = (const float*)d_in[0];
    const float* key_  = (const float*)d_in[1];
    const float* value = (const float*)d_in[2];
    const float* Wq = (const float*)d_in[3];
    const float* bq = (const float*)d_in[4];
    const float* Wk = (const float*)d_in[5];
    const float* bk = (const float*)d_in[6];
    const float* Wv = (const float*)d_in[7];
    const float* bv = (const float*)d_in[8];
    const float* Wo = (const float*)d_in[9];
    const float* bo = (const float*)d_in[10];

    float* out  = (float*)d_out;
    float* attn = out + (size_t)NTOK * DMODEL;

    const size_t MM = (size_t)1024 * 1024;
    _Float16* ws16 = (_Float16*)d_ws;          // 32 MB used
    _Float16* Wt  = ws16;                      // 8 planes (Wq,Wk,Wv,Wo x hi/lo), 16 MB
    _Float16* Qh  = ws16 + 8 * MM;             // 4 x 4 MB planes
    _Float16* Ql  = Qh  + 2 * MM;
    _Float16* Kh_ = Ql  + 2 * MM;
    _Float16* Vth = Kh_ + 2 * MM;

    // dead-after-qkv alias: Xp (8 MB) over Wq/Wk hi planes
    float* Xp = (float*)ws16;

    // A-split scratch lives in the attn output region (dead until fused_attn rewrites it)
    _Float16* As = (_Float16*)attn;            // 12 MB of 268 MB

    dim3 blk(256);
    prep_w_kernel<<<dim3(32, 32, 4), blk, 0, stream>>>(Wq, Wk, Wv, Wo, Wt);
    prep_a_kernel<<<dim3(1024, 3), blk, 0, stream>>>(query, key_, value, As);
    qkv_mfma_kernel<<<dim3(8, 32, 3), blk, 0, stream>>>(As, Wt, bq, bk, bv,
                                                        Qh, Ql, Kh_, Vth);
    fused_attn_kernel<<<dim3(16, 16), blk, 0, stream>>>(Qh, Ql, Kh_, Vth, attn, Xp);
    out_mfma_kernel<<<dim3(8, 32), blk, 0, stream>>>(Xp, Wt + 6 * MM, Wt + 7 * MM, bo, out);
}

// Round 17
// 216.357 us; speedup vs baseline: 1.0765x; 1.0066x over previous
//
#include <hip/hip_runtime.h>
#include <math.h>

#define NTOK 2048
#define DMODEL 1024
#define NHEAD 16
#define DHEAD 64
#define NTIL (NTOK / 64)   // 32 K-tiles total
#define HTIL (NTIL / 2)    // 16 per K-half group

typedef _Float16 f16x8 __attribute__((ext_vector_type(8)));
typedef _Float16 f16x4 __attribute__((ext_vector_type(4)));
typedef _Float16 f16x2 __attribute__((ext_vector_type(2)));
typedef float f32x4 __attribute__((ext_vector_type(4)));
typedef float f32x16 __attribute__((ext_vector_type(16)));

union U32H2 { f16x2 h; unsigned u; };
union U8 { f16x8 v; unsigned u[4]; };

__device__ __forceinline__ void split16(float x, _Float16& hi, _Float16& lo) {
    hi = (_Float16)x;
    lo = (_Float16)(x - (float)hi);
}
__device__ __forceinline__ unsigned packh(_Float16 a, _Float16 b) {
    U32H2 c; c.h = f16x2{a, b}; return c.u;
}

// ---------- prep: W[k][n] f32 -> Wt_hi/Wt_lo [n][k] f16, 4 matrices ----------
__global__ void __launch_bounds__(256) prep_w_kernel(
        const float* __restrict__ Wq, const float* __restrict__ Wk,
        const float* __restrict__ Wv, const float* __restrict__ Wo,
        _Float16* __restrict__ Wt) {
    __shared__ float T[32][33];
    const int z = blockIdx.z;
    const float* W = (z == 0) ? Wq : (z == 1) ? Wk : (z == 2) ? Wv : Wo;
    _Float16* Whi = Wt + (size_t)z * 2 * 1024 * 1024;
    _Float16* Wlo = Whi + (size_t)1024 * 1024;
    const int t = threadIdx.x;
    const int k0 = blockIdx.y * 32, n0 = blockIdx.x * 32;
    const int r = t >> 3, c4 = (t & 7) * 4;
    const float4 v = *(const float4*)(W + (size_t)(k0 + r) * DMODEL + n0 + c4);
    T[r][c4 + 0] = v.x; T[r][c4 + 1] = v.y; T[r][c4 + 2] = v.z; T[r][c4 + 3] = v.w;
    __syncthreads();
    f16x4 hv, lv;
#pragma unroll
    for (int j = 0; j < 4; ++j) {
        _Float16 h, l;
        split16(T[c4 + j][r], h, l);
        hv[j] = h; lv[j] = l;
    }
    *(f16x4*)(Whi + (size_t)(n0 + r) * DMODEL + k0 + c4) = hv;
    *(f16x4*)(Wlo + (size_t)(n0 + r) * DMODEL + k0 + c4) = lv;
}

// ---------- prep: A (query/key/value) f32 -> hi/lo f16 planes ----------
__global__ void __launch_bounds__(256) prep_a_kernel(
        const float* __restrict__ q, const float* __restrict__ k, const float* __restrict__ v,
        _Float16* __restrict__ As) {   // layout: [z][hi/lo][2048*1024]
    const int z = blockIdx.y;
    const float* A = (z == 0) ? q : (z == 1) ? k : v;
    const size_t PL = (size_t)NTOK * DMODEL;
    _Float16* H = As + (size_t)z * 2 * PL;
    _Float16* L = H + PL;
    const size_t off = ((size_t)blockIdx.x * 256 + threadIdx.x) * 8;
    const float4 a = *(const float4*)(A + off);
    const float4 b = *(const float4*)(A + off + 4);
    f16x8 hv, lv; _Float16 h, lo;
    split16(a.x, h, lo); hv[0] = h; lv[0] = lo;
    split16(a.y, h, lo); hv[1] = h; lv[1] = lo;
    split16(a.z, h, lo); hv[2] = h; lv[2] = lo;
    split16(a.w, h, lo); hv[3] = h; lv[3] = lo;
    split16(b.x, h, lo); hv[4] = h; lv[4] = lo;
    split16(b.y, h, lo); hv[5] = h; lv[5] = lo;
    split16(b.z, h, lo); hv[6] = h; lv[6] = lo;
    split16(b.w, h, lo); hv[7] = h; lv[7] = lo;
    *(f16x8*)(H + off) = hv;
    *(f16x8*)(L + off) = lv;
}

// ---------- QKV projection: pre-split f16 MFMA GEMM, 64x128 tile, grid-balanced ----------
// Outputs: z=0 -> Qh+Ql (x0.125); z=1 -> Kh only; z=2 -> Vth only.
__global__ void __launch_bounds__(256) qkv_mfma_kernel(
        const _Float16* __restrict__ As,
        const _Float16* __restrict__ Wt,
        const float* __restrict__ bq, const float* __restrict__ bk, const float* __restrict__ bv,
        _Float16* __restrict__ Qh, _Float16* __restrict__ Ql,
        _Float16* __restrict__ Kh, _Float16* __restrict__ Vth) {
    __shared__ _Float16 Ah[64][40], Al[64][40], Bh[128][40], Bl[128][40];
    const int z = blockIdx.z;
    const size_t PL = (size_t)NTOK * DMODEL;
    const _Float16* AH = As + (size_t)z * 2 * PL;
    const _Float16* AL = AH + PL;
    const _Float16* WH = Wt + (size_t)z * 2 * 1024 * 1024;
    const _Float16* WL = WH + (size_t)1024 * 1024;
    const float* bias = (z == 0) ? bq : (z == 1) ? bk : bv;

    const int t = threadIdx.x;
    const int l = t & 63, wid = t >> 6;
    const int lr = l & 15, lk = l >> 4;
    const int m0 = blockIdx.y * 64, n0 = blockIdx.x * 128;
    const int wm = (wid >> 1) * 32, wn = (wid & 1) * 64;

    f32x4 acc[2][4];
#pragma unroll
    for (int mi = 0; mi < 2; ++mi)
#pragma unroll
        for (int ni = 0; ni < 4; ++ni)
#pragma unroll
            for (int e = 0; e < 4; ++e) acc[mi][ni][e] = 0.f;

    for (int k0 = 0; k0 < DMODEL; k0 += 32) {
        __syncthreads();
        {   // A: pre-split f16, 64x32 per plane
            const int r = t >> 2, c8 = (t & 3) * 8;
            *(f16x8*)&Ah[r][c8] = *(const f16x8*)(AH + (size_t)(m0 + r) * DMODEL + k0 + c8);
            *(f16x8*)&Al[r][c8] = *(const f16x8*)(AL + (size_t)(m0 + r) * DMODEL + k0 + c8);
        }
#pragma unroll
        for (int p = 0; p < 2; ++p) {   // B: 128x32 per plane
            const int idx = t + p * 256;
            const int r = idx >> 2, c8 = (idx & 3) * 8;
            *(f16x8*)&Bh[r][c8] = *(const f16x8*)(WH + (size_t)(n0 + r) * DMODEL + k0 + c8);
            *(f16x8*)&Bl[r][c8] = *(const f16x8*)(WL + (size_t)(n0 + r) * DMODEL + k0 + c8);
        }
        __syncthreads();

        f16x8 ah[2], al[2], bh[4], bl[4];
#pragma unroll
        for (int i = 0; i < 2; ++i) {
            ah[i] = *(f16x8*)&Ah[wm + i * 16 + lr][lk * 8];
            al[i] = *(f16x8*)&Al[wm + i * 16 + lr][lk * 8];
        }
#pragma unroll
        for (int i = 0; i < 4; ++i) {
            bh[i] = *(f16x8*)&Bh[wn + i * 16 + lr][lk * 8];
            bl[i] = *(f16x8*)&Bl[wn + i * 16 + lr][lk * 8];
        }
        __builtin_amdgcn_s_setprio(1);
#pragma unroll
        for (int mi = 0; mi < 2; ++mi)
#pragma unroll
            for (int ni = 0; ni < 4; ++ni) {
                acc[mi][ni] = __builtin_amdgcn_mfma_f32_16x16x32_f16(ah[mi], bh[ni], acc[mi][ni], 0, 0, 0);
                acc[mi][ni] = __builtin_amdgcn_mfma_f32_16x16x32_f16(ah[mi], bl[ni], acc[mi][ni], 0, 0, 0);
                acc[mi][ni] = __builtin_amdgcn_mfma_f32_16x16x32_f16(al[mi], bh[ni], acc[mi][ni], 0, 0, 0);
            }
        __builtin_amdgcn_s_setprio(0);
    }

#pragma unroll
    for (int ni = 0; ni < 4; ++ni) {
        const int col = n0 + wn + ni * 16 + lr;
        const float bv_ = bias[col];
#pragma unroll
        for (int mi = 0; mi < 2; ++mi) {
            if (z == 2) {
                f16x4 hv;
#pragma unroll
                for (int i = 0; i < 4; ++i) hv[i] = (_Float16)(acc[mi][ni][i] + bv_);
                const int row = m0 + wm + mi * 16 + lk * 4;
                *(f16x4*)(Vth + (size_t)col * NTOK + row) = hv;
            } else {
#pragma unroll
                for (int i = 0; i < 4; ++i) {
                    const int row = m0 + wm + mi * 16 + lk * 4 + i;
                    float v = acc[mi][ni][i] + bv_;
                    if (z == 0) {
                        v *= 0.125f;
                        _Float16 h, lo;
                        split16(v, h, lo);
                        Qh[(size_t)row * DMODEL + col] = h;
                        Ql[(size_t)row * DMODEL + col] = lo;
                    } else {
                        Kh[(size_t)row * DMODEL + col] = (_Float16)v;
                    }
                }
            }
        }
    }
}

// ---------- fused attention: 512 threads = 4 q-subblocks x 2 K-half groups ----------
// grid (16, 16): x = q-block of 128 rows, y = head. 8 waves/CU = 2/SIMD.
__global__ void __launch_bounds__(512, 2) fused_attn_kernel(
        const _Float16* __restrict__ Qh, const _Float16* __restrict__ Ql,
        const _Float16* __restrict__ Kh, const _Float16* __restrict__ Vth,
        float* __restrict__ attn, float* __restrict__ Xp) {
    __shared__ _Float16 KB[2][2][64][64];   // [kgroup][buf] 32 KB
    __shared__ _Float16 VB[2][2][64][64];   // 32 KB
    const int t = threadIdx.x, l = t & 63, w = t >> 6, q = l & 31, h = l >> 5;
    const int qsub = w & 3, kg = w >> 2;
    const int hh = blockIdx.y;
    const int rw = blockIdx.x * 128 + qsub * 32;
    const int tg = t & 255;                 // group-local thread id
    const int sr = tg >> 3, sc = tg & 7;
    const int qrow = rw + q;
    const int jb = kg * HTIL;               // first tile index of my K-half

    f16x8 qbh[4], qbl[4];
#pragma unroll
    for (int s = 0; s < 4; ++s) {
        const size_t off = (size_t)qrow * DMODEL + hh * DHEAD + s * 16 + h * 8;
        qbh[s] = *(const f16x8*)(Qh + off);
        qbl[s] = *(const f16x8*)(Ql + off);
    }

    auto stageK = [&](int buf, int tile) {
        const int j0 = tile * 64;
#pragma unroll
        for (int p = 0; p < 2; ++p) {
            const int r = sr + p * 32; const int cs = (sc ^ (r & 7)) * 8;
            *(f16x8*)&KB[kg][buf][r][cs] = *(const f16x8*)(Kh + (size_t)(j0 + r) * DMODEL + hh * DHEAD + sc * 8);
        }
    };
    auto stageV = [&](int buf, int tile) {
        const int j0 = tile * 64;
#pragma unroll
        for (int p = 0; p < 2; ++p) {
            const int r = sr + p * 32; const int cs = (sc ^ (r & 7)) * 8;
            *(f16x8*)&VB[kg][buf][r][cs] = *(const f16x8*)(Vth + (size_t)(hh * DHEAD + r) * NTOK + j0 + sc * 8);
        }
    };
    auto qkt = [&](int buf, f32x16 (&c)[2]) {
#pragma unroll
        for (int kb = 0; kb < 2; ++kb) {
#pragma unroll
            for (int r = 0; r < 16; ++r) c[kb][r] = 0.f;
            __builtin_amdgcn_s_setprio(1);
#pragma unroll
            for (int s = 0; s < 4; ++s) {
                const int rk = kb * 32 + q; const int cc = ((2 * s + h) ^ (rk & 7)) * 8;
                const f16x8 ah = *(f16x8*)&KB[kg][buf][rk][cc];
                c[kb] = __builtin_amdgcn_mfma_f32_32x32x16_f16(ah, qbh[s], c[kb], 0, 0, 0);
                c[kb] = __builtin_amdgcn_mfma_f32_32x32x16_f16(ah, qbl[s], c[kb], 0, 0, 0);
            }
            __builtin_amdgcn_s_setprio(0);
        }
    };

    // ---- pass 1: partial l over my K-half ----
    float lsum = 0.f;
    stageK(0, jb);
    for (int it = 0; it < HTIL; ++it) {
        __syncthreads();
        if (it + 1 < HTIL) stageK((it + 1) & 1, jb + it + 1);
        f32x16 c[2];
        qkt(it & 1, c);
#pragma unroll
        for (int kb = 0; kb < 2; ++kb)
#pragma unroll
            for (int r = 0; r < 16; ++r) lsum += __expf(c[kb][r]);
    }
    lsum += __shfl_xor(lsum, 32);

    // combine partial l across the two K-half groups (VB unused in pass 1)
    float* ls = (float*)VB;
    if (h == 0) ls[w * 32 + q] = lsum;
    __syncthreads();
    const float linv = 1.f / (ls[qsub * 32 + q] + ls[(qsub + 4) * 32 + q]);
    __syncthreads();   // ls reads done before pass-2 staging overwrites VB

    // ---- pass 2: my K-half — recompute s, write attn, partial PV ----
    f32x16 x0, x1;
#pragma unroll
    for (int r = 0; r < 16; ++r) { x0[r] = 0.f; x1[r] = 0.f; }

    stageK(0, jb);
    stageV(0, jb);
    for (int it = 0; it < HTIL; ++it) {
        const int j0 = (jb + it) * 64;
        __syncthreads();
        const int cur = it & 1;
        if (it + 1 < HTIL) { stageK(cur ^ 1, jb + it + 1); stageV(cur ^ 1, jb + it + 1); }

        f32x16 c[2];
        qkt(cur, c);

#pragma unroll
        for (int kb = 0; kb < 2; ++kb) {
            float p[16];
#pragma unroll
            for (int r = 0; r < 16; ++r) p[r] = __expf(c[kb][r]) * linv;

            const int kbase = j0 + kb * 32;
#pragma unroll
            for (int i = 0; i < 4; ++i) {
                f32x4 st;
                st[0] = p[4 * i]; st[1] = p[4 * i + 1]; st[2] = p[4 * i + 2]; st[3] = p[4 * i + 3];
                *(f32x4*)(attn + ((size_t)hh * NTOK + qrow) * NTOK + kbase + 8 * i + 4 * h) = st;
            }

            _Float16 hf[16];
#pragma unroll
            for (int r = 0; r < 16; ++r) hf[r] = (_Float16)p[r];
            unsigned ph[8];
#pragma unroll
            for (int i = 0; i < 8; ++i) ph[i] = packh(hf[2 * i], hf[2 * i + 1]);

#pragma unroll
            for (int ss = 0; ss < 2; ++ss) {
                const int b = 4 * ss;
                const unsigned eh0 = __shfl_xor(h ? ph[b + 0] : ph[b + 2], 32);
                const unsigned eh1 = __shfl_xor(h ? ph[b + 1] : ph[b + 3], 32);
                U8 pah;
                pah.u[0] = h ? eh0 : ph[b + 0]; pah.u[1] = h ? eh1 : ph[b + 1];
                pah.u[2] = h ? ph[b + 2] : eh0; pah.u[3] = h ? ph[b + 3] : eh1;
                const int ks = kb * 2 + ss;
                __builtin_amdgcn_s_setprio(1);
                {
                    const int rd0 = q; const int cv0 = ((2 * ks + h) ^ (rd0 & 7)) * 8;
                    const f16x8 vh = *(f16x8*)&VB[kg][cur][rd0][cv0];
                    x0 = __builtin_amdgcn_mfma_f32_32x32x16_f16(pah.v, vh, x0, 0, 0, 0);
                }
                {
                    const int rd1 = 32 + q; const int cv1 = ((2 * ks + h) ^ (rd1 & 7)) * 8;
                    const f16x8 vh = *(f16x8*)&VB[kg][cur][rd1][cv1];
                    x1 = __builtin_amdgcn_mfma_f32_32x32x16_f16(pah.v, vh, x1, 0, 0, 0);
                }
                __builtin_amdgcn_s_setprio(0);
            }
        }
    }

    // ---- combine partial X across K-half groups (reuse KB as f32 scratch, 32 KB) ----
    __syncthreads();   // all LDS tile reads complete
    float* xs = (float*)KB;
    if (kg == 1) {
#pragma unroll
        for (int r = 0; r < 16; ++r) {
            xs[((qsub * 64) + l) * 32 + r]      = x0[r];
            xs[((qsub * 64) + l) * 32 + 16 + r] = x1[r];
        }
    }
    __syncthreads();
    if (kg == 0) {
#pragma unroll
        for (int r = 0; r < 16; ++r) {
            x0[r] += xs[((qsub * 64) + l) * 32 + r];
            x1[r] += xs[((qsub * 64) + l) * 32 + 16 + r];
        }
#pragma unroll
        for (int r = 0; r < 16; ++r) {
            const int qloc = (r & 3) + 8 * (r >> 2) + 4 * h;
            Xp[(size_t)(rw + qloc) * DMODEL + hh * DHEAD + q]      = x0[r];
            Xp[(size_t)(rw + qloc) * DMODEL + hh * DHEAD + 32 + q] = x1[r];
        }
    }
}

// ---------- output projection: A = Xp (f32) -> split, 64x128 tile ----------
__global__ void __launch_bounds__(256) out_mfma_kernel(
        const float* __restrict__ Xp,
        const _Float16* __restrict__ WH, const _Float16* __restrict__ WL,
        const float* __restrict__ bo, float* __restrict__ out) {
    __shared__ _Float16 Ah[64][40], Al[64][40], Bh[128][40], Bl[128][40];
    const int t = threadIdx.x;
    const int l = t & 63, wid = t >> 6;
    const int lr = l & 15, lk = l >> 4;
    const int m0 = blockIdx.y * 64, n0 = blockIdx.x * 128;
    const int wm = (wid >> 1) * 32, wn = (wid & 1) * 64;

    f32x4 acc[2][4];
#pragma unroll
    for (int mi = 0; mi < 2; ++mi)
#pragma unroll
        for (int ni = 0; ni < 4; ++ni)
#pragma unroll
            for (int e = 0; e < 4; ++e) acc[mi][ni][e] = 0.f;

    for (int k0 = 0; k0 < DMODEL; k0 += 32) {
        __syncthreads();
#pragma unroll
        for (int p = 0; p < 2; ++p) {
            const int idx = t + p * 256;
            const int r = idx >> 3, c4 = (idx & 7) * 4;
            const size_t off = (size_t)(m0 + r) * DMODEL + k0 + c4;
            const float4 v0 = *(const float4*)(Xp + off);
            f16x4 hv, lv; _Float16 h, lo;
            split16(v0.x, h, lo); hv[0] = h; lv[0] = lo;
            split16(v0.y, h, lo); hv[1] = h; lv[1] = lo;
            split16(v0.z, h, lo); hv[2] = h; lv[2] = lo;
            split16(v0.w, h, lo); hv[3] = h; lv[3] = lo;
            *(f16x4*)&Ah[r][c4] = hv;
            *(f16x4*)&Al[r][c4] = lv;
        }
#pragma unroll
        for (int p = 0; p < 2; ++p) {
            const int idx = t + p * 256;
            const int r = idx >> 2, c8 = (idx & 3) * 8;
            *(f16x8*)&Bh[r][c8] = *(const f16x8*)(WH + (size_t)(n0 + r) * DMODEL + k0 + c8);
            *(f16x8*)&Bl[r][c8] = *(const f16x8*)(WL + (size_t)(n0 + r) * DMODEL + k0 + c8);
        }
        __syncthreads();

        f16x8 ah[2], al[2], bh[4], bl[4];
#pragma unroll
        for (int i = 0; i < 2; ++i) {
            ah[i] = *(f16x8*)&Ah[wm + i * 16 + lr][lk * 8];
            al[i] = *(f16x8*)&Al[wm + i * 16 + lr][lk * 8];
        }
#pragma unroll
        for (int i = 0; i < 4; ++i) {
            bh[i] = *(f16x8*)&Bh[wn + i * 16 + lr][lk * 8];
            bl[i] = *(f16x8*)&Bl[wn + i * 16 + lr][lk * 8];
        }
        __builtin_amdgcn_s_setprio(1);
#pragma unroll
        for (int mi = 0; mi < 2; ++mi)
#pragma unroll
            for (int ni = 0; ni < 4; ++ni) {
                acc[mi][ni] = __builtin_amdgcn_mfma_f32_16x16x32_f16(ah[mi], bh[ni], acc[mi][ni], 0, 0, 0);
                acc[mi][ni] = __builtin_amdgcn_mfma_f32_16x16x32_f16(ah[mi], bl[ni], acc[mi][ni], 0, 0, 0);
                acc[mi][ni] = __builtin_amdgcn_mfma_f32_16x16x32_f16(al[mi], bh[ni], acc[mi][ni], 0, 0, 0);
            }
        __builtin_amdgcn_s_setprio(0);
    }

#pragma unroll
    for (int ni = 0; ni < 4; ++ni) {
        const int col = n0 + wn + ni * 16 + lr;
        const float bv_ = bo[col];
#pragma unroll
        for (int mi = 0; mi < 2; ++mi)
#pragma unroll
            for (int i = 0; i < 4; ++i) {
                const int row = m0 + wm + mi * 16 + lk * 4 + i;
                out[(size_t)row * DMODEL + col] = acc[mi][ni][i] + bv_;
            }
    }
}

extern "C" void kernel_launch(void* const* d_in, const int* in_sizes, int n_in,
                              void* d_out, int out_size, void* d_ws, size_t ws_size,
                              hipStream_t stream) {
    (void)in_sizes; (void)n_in; (void)out_size; (void)ws_size;
    const float* query = (const float*)d_in[0];
    const float* key_  = (const float*)d_in[1];
    const float* value = (const float*)d_in[2];
    const float* Wq = (const float*)d_in[3];
    const float* bq = (const float*)d_in[4];
    const float* Wk = (const float*)d_in[5];
    const float* bk = (const float*)d_in[6];
    const float* Wv = (const float*)d_in[7];
    const float* bv = (const float*)d_in[8];
    const float* Wo = (const float*)d_in[9];
    const float* bo = (const float*)d_in[10];

    float* out  = (float*)d_out;
    float* attn = out + (size_t)NTOK * DMODEL;

    const size_t MM = (size_t)1024 * 1024;
    _Float16* ws16 = (_Float16*)d_ws;          // 32 MB used
    _Float16* Wt  = ws16;                      // 8 planes (Wq,Wk,Wv,Wo x hi/lo), 16 MB
    _Float16* Qh  = ws16 + 8 * MM;             // 4 x 4 MB planes
    _Float16* Ql  = Qh  + 2 * MM;
    _Float16* Kh_ = Ql  + 2 * MM;
    _Float16* Vth = Kh_ + 2 * MM;

    // dead-after-qkv alias: Xp (8 MB) over Wq/Wk hi planes
    float* Xp = (float*)ws16;

    // A-split scratch lives in the attn output region (dead until fused_attn rewrites it)
    _Float16* As = (_Float16*)attn;            // 12 MB of 268 MB

    dim3 blk(256);
    prep_w_kernel<<<dim3(32, 32, 4), blk, 0, stream>>>(Wq, Wk, Wv, Wo, Wt);
    prep_a_kernel<<<dim3(1024, 3), blk, 0, stream>>>(query, key_, value, As);
    qkv_mfma_kernel<<<dim3(8, 32, 3), blk, 0, stream>>>(As, Wt, bq, bk, bv,
                                                        Qh, Ql, Kh_, Vth);
    fused_attn_kernel<<<dim3(16, 16), dim3(512), 0, stream>>>(Qh, Ql, Kh_, Vth, attn, Xp);
    out_mfma_kernel<<<dim3(8, 32), blk, 0, stream>>>(Xp, Wt + 6 * MM, Wt + 7 * MM, bo, out);
}

// Round 18
// 213.986 us; speedup vs baseline: 1.0885x; 1.0111x over previous
//
#include <hip/hip_runtime.h>
#include <math.h>

#define NTOK 2048
#define DMODEL 1024
#define NHEAD 16
#define DHEAD 64
#define NTIL (NTOK / 64)   // 32 K-tiles total
#define HTIL (NTIL / 2)    // 16 per K-half group

typedef _Float16 f16x8 __attribute__((ext_vector_type(8)));
typedef _Float16 f16x4 __attribute__((ext_vector_type(4)));
typedef _Float16 f16x2 __attribute__((ext_vector_type(2)));
typedef float f32x4 __attribute__((ext_vector_type(4)));
typedef float f32x16 __attribute__((ext_vector_type(16)));

union U32H2 { f16x2 h; unsigned u; };
union U8 { f16x8 v; unsigned u[4]; };

__device__ __forceinline__ void split16(float x, _Float16& hi, _Float16& lo) {
    hi = (_Float16)x;
    lo = (_Float16)(x - (float)hi);
}
__device__ __forceinline__ unsigned packh(_Float16 a, _Float16 b) {
    U32H2 c; c.h = f16x2{a, b}; return c.u;
}

#define GLD16(gsrc, ldst)                                                             \
    __builtin_amdgcn_global_load_lds(                                                 \
        (const __attribute__((address_space(1))) void*)(gsrc),                        \
        (__attribute__((address_space(3))) void*)(ldst), 16, 0, 0)

// ---------- prep: W[k][n] f32 -> Wt_hi/Wt_lo [n][k] f16, 4 matrices ----------
__global__ void __launch_bounds__(256) prep_w_kernel(
        const float* __restrict__ Wq, const float* __restrict__ Wk,
        const float* __restrict__ Wv, const float* __restrict__ Wo,
        _Float16* __restrict__ Wt) {
    __shared__ float T[32][33];
    const int z = blockIdx.z;
    const float* W = (z == 0) ? Wq : (z == 1) ? Wk : (z == 2) ? Wv : Wo;
    _Float16* Whi = Wt + (size_t)z * 2 * 1024 * 1024;
    _Float16* Wlo = Whi + (size_t)1024 * 1024;
    const int t = threadIdx.x;
    const int k0 = blockIdx.y * 32, n0 = blockIdx.x * 32;
    const int r = t >> 3, c4 = (t & 7) * 4;
    const float4 v = *(const float4*)(W + (size_t)(k0 + r) * DMODEL + n0 + c4);
    T[r][c4 + 0] = v.x; T[r][c4 + 1] = v.y; T[r][c4 + 2] = v.z; T[r][c4 + 3] = v.w;
    __syncthreads();
    f16x4 hv, lv;
#pragma unroll
    for (int j = 0; j < 4; ++j) {
        _Float16 h, l;
        split16(T[c4 + j][r], h, l);
        hv[j] = h; lv[j] = l;
    }
    *(f16x4*)(Whi + (size_t)(n0 + r) * DMODEL + k0 + c4) = hv;
    *(f16x4*)(Wlo + (size_t)(n0 + r) * DMODEL + k0 + c4) = lv;
}

// ---------- prep: A (query/key/value) f32 -> hi/lo f16 planes ----------
__global__ void __launch_bounds__(256) prep_a_kernel(
        const float* __restrict__ q, const float* __restrict__ k, const float* __restrict__ v,
        _Float16* __restrict__ As) {   // layout: [z][hi/lo][2048*1024]
    const int z = blockIdx.y;
    const float* A = (z == 0) ? q : (z == 1) ? k : v;
    const size_t PL = (size_t)NTOK * DMODEL;
    _Float16* H = As + (size_t)z * 2 * PL;
    _Float16* L = H + PL;
    const size_t off = ((size_t)blockIdx.x * 256 + threadIdx.x) * 8;
    const float4 a = *(const float4*)(A + off);
    const float4 b = *(const float4*)(A + off + 4);
    f16x8 hv, lv; _Float16 h, lo;
    split16(a.x, h, lo); hv[0] = h; lv[0] = lo;
    split16(a.y, h, lo); hv[1] = h; lv[1] = lo;
    split16(a.z, h, lo); hv[2] = h; lv[2] = lo;
    split16(a.w, h, lo); hv[3] = h; lv[3] = lo;
    split16(b.x, h, lo); hv[4] = h; lv[4] = lo;
    split16(b.y, h, lo); hv[5] = h; lv[5] = lo;
    split16(b.z, h, lo); hv[6] = h; lv[6] = lo;
    split16(b.w, h, lo); hv[7] = h; lv[7] = lo;
    *(f16x8*)(H + off) = hv;
    *(f16x8*)(L + off) = lv;
}

// ---------- QKV projection: global_load_lds staging, rotation-swizzled [.][32] LDS ----------
// Outputs: z=0 -> Qh+Ql (x0.125); z=1 -> Kh only; z=2 -> Vth only.
__global__ void __launch_bounds__(256) qkv_mfma_kernel(
        const _Float16* __restrict__ As,
        const _Float16* __restrict__ Wt,
        const float* __restrict__ bq, const float* __restrict__ bk, const float* __restrict__ bv,
        _Float16* __restrict__ Qh, _Float16* __restrict__ Ql,
        _Float16* __restrict__ Kh, _Float16* __restrict__ Vth) {
    __shared__ _Float16 Ah[64][32], Al[64][32], Bh[128][32], Bl[128][32];
    const int z = blockIdx.z;
    const size_t PL = (size_t)NTOK * DMODEL;
    const _Float16* AH = As + (size_t)z * 2 * PL;
    const _Float16* AL = AH + PL;
    const _Float16* WH = Wt + (size_t)z * 2 * 1024 * 1024;
    const _Float16* WL = WH + (size_t)1024 * 1024;
    const float* bias = (z == 0) ? bq : (z == 1) ? bk : bv;

    const int t = threadIdx.x;
    const int l = t & 63, wid = t >> 6;
    const int lr = l & 15, lk = l >> 4;
    const int m0 = blockIdx.y * 64, n0 = blockIdx.x * 128;
    const int wm = (wid >> 1) * 32, wn = (wid & 1) * 64;

    // staging geometry: LDS slot t (16B units) -> row r, slot-unit su; global col unit eu
    const int srA = t >> 2, suA = t & 3;
    const int euA = (suA + 4 - ((srA >> 1) & 3)) & 3;
    const char* AhB = (const char*)&Ah[0][0];
    const char* AlB = (const char*)&Al[0][0];
    const char* BhB = (const char*)&Bh[0][0];
    const char* BlB = (const char*)&Bl[0][0];
    char* AhW = (char*)&Ah[0][0] + wid * 1024;
    char* AlW = (char*)&Al[0][0] + wid * 1024;

    f32x4 acc[2][4];
#pragma unroll
    for (int mi = 0; mi < 2; ++mi)
#pragma unroll
        for (int ni = 0; ni < 4; ++ni)
#pragma unroll
            for (int e = 0; e < 4; ++e) acc[mi][ni][e] = 0.f;

    for (int k0 = 0; k0 < DMODEL; k0 += 32) {
        __syncthreads();
        // A planes: 4KB each = 1 x 16B per thread (DMA, source pre-swizzled)
        GLD16(AH + (size_t)(m0 + srA) * DMODEL + k0 + euA * 8, AhW);
        GLD16(AL + (size_t)(m0 + srA) * DMODEL + k0 + euA * 8, AlW);
        // B planes: 8KB each = 2 x 16B per thread
#pragma unroll
        for (int p = 0; p < 2; ++p) {
            const int slot = p * 256 + t;
            const int rb = slot >> 2, sub = slot & 3;
            const int eub = (sub + 4 - ((rb >> 1) & 3)) & 3;
            char* dstH = (char*)&Bh[0][0] + p * 4096 + wid * 1024;
            char* dstL = (char*)&Bl[0][0] + p * 4096 + wid * 1024;
            GLD16(WH + (size_t)(n0 + rb) * DMODEL + k0 + eub * 8, dstH);
            GLD16(WL + (size_t)(n0 + rb) * DMODEL + k0 + eub * 8, dstL);
        }
        __syncthreads();

        f16x8 ah[2], al[2], bh[4], bl[4];
#pragma unroll
        for (int i = 0; i < 2; ++i) {
            const int row = wm + i * 16 + lr;
            const int off = row * 64 + (((lk + (row >> 1)) & 3) * 16);
            ah[i] = *(const f16x8*)(AhB + off);
            al[i] = *(const f16x8*)(AlB + off);
        }
#pragma unroll
        for (int i = 0; i < 4; ++i) {
            const int row = wn + i * 16 + lr;
            const int off = row * 64 + (((lk + (row >> 1)) & 3) * 16);
            bh[i] = *(const f16x8*)(BhB + off);
            bl[i] = *(const f16x8*)(BlB + off);
        }
        __builtin_amdgcn_s_setprio(1);
#pragma unroll
        for (int mi = 0; mi < 2; ++mi)
#pragma unroll
            for (int ni = 0; ni < 4; ++ni) {
                acc[mi][ni] = __builtin_amdgcn_mfma_f32_16x16x32_f16(ah[mi], bh[ni], acc[mi][ni], 0, 0, 0);
                acc[mi][ni] = __builtin_amdgcn_mfma_f32_16x16x32_f16(ah[mi], bl[ni], acc[mi][ni], 0, 0, 0);
                acc[mi][ni] = __builtin_amdgcn_mfma_f32_16x16x32_f16(al[mi], bh[ni], acc[mi][ni], 0, 0, 0);
            }
        __builtin_amdgcn_s_setprio(0);
    }

#pragma unroll
    for (int ni = 0; ni < 4; ++ni) {
        const int col = n0 + wn + ni * 16 + lr;
        const float bv_ = bias[col];
#pragma unroll
        for (int mi = 0; mi < 2; ++mi) {
            if (z == 2) {
                f16x4 hv;
#pragma unroll
                for (int i = 0; i < 4; ++i) hv[i] = (_Float16)(acc[mi][ni][i] + bv_);
                const int row = m0 + wm + mi * 16 + lk * 4;
                *(f16x4*)(Vth + (size_t)col * NTOK + row) = hv;
            } else {
#pragma unroll
                for (int i = 0; i < 4; ++i) {
                    const int row = m0 + wm + mi * 16 + lk * 4 + i;
                    float v = acc[mi][ni][i] + bv_;
                    if (z == 0) {
                        v *= 0.125f;
                        _Float16 h, lo;
                        split16(v, h, lo);
                        Qh[(size_t)row * DMODEL + col] = h;
                        Ql[(size_t)row * DMODEL + col] = lo;
                    } else {
                        Kh[(size_t)row * DMODEL + col] = (_Float16)v;
                    }
                }
            }
        }
    }
}

// ---------- fused attention: 512 threads = 4 q-subblocks x 2 K-half groups (R17) ----------
__global__ void __launch_bounds__(512, 2) fused_attn_kernel(
        const _Float16* __restrict__ Qh, const _Float16* __restrict__ Ql,
        const _Float16* __restrict__ Kh, const _Float16* __restrict__ Vth,
        float* __restrict__ attn, float* __restrict__ Xp) {
    __shared__ _Float16 KB[2][2][64][64];
    __shared__ _Float16 VB[2][2][64][64];
    const int t = threadIdx.x, l = t & 63, w = t >> 6, q = l & 31, h = l >> 5;
    const int qsub = w & 3, kg = w >> 2;
    const int hh = blockIdx.y;
    const int rw = blockIdx.x * 128 + qsub * 32;
    const int tg = t & 255;
    const int sr = tg >> 3, sc = tg & 7;
    const int qrow = rw + q;
    const int jb = kg * HTIL;

    f16x8 qbh[4], qbl[4];
#pragma unroll
    for (int s = 0; s < 4; ++s) {
        const size_t off = (size_t)qrow * DMODEL + hh * DHEAD + s * 16 + h * 8;
        qbh[s] = *(const f16x8*)(Qh + off);
        qbl[s] = *(const f16x8*)(Ql + off);
    }

    auto stageK = [&](int buf, int tile) {
        const int j0 = tile * 64;
#pragma unroll
        for (int p = 0; p < 2; ++p) {
            const int r = sr + p * 32; const int cs = (sc ^ (r & 7)) * 8;
            *(f16x8*)&KB[kg][buf][r][cs] = *(const f16x8*)(Kh + (size_t)(j0 + r) * DMODEL + hh * DHEAD + sc * 8);
        }
    };
    auto stageV = [&](int buf, int tile) {
        const int j0 = tile * 64;
#pragma unroll
        for (int p = 0; p < 2; ++p) {
            const int r = sr + p * 32; const int cs = (sc ^ (r & 7)) * 8;
            *(f16x8*)&VB[kg][buf][r][cs] = *(const f16x8*)(Vth + (size_t)(hh * DHEAD + r) * NTOK + j0 + sc * 8);
        }
    };
    auto qkt = [&](int buf, f32x16 (&c)[2]) {
#pragma unroll
        for (int kb = 0; kb < 2; ++kb) {
#pragma unroll
            for (int r = 0; r < 16; ++r) c[kb][r] = 0.f;
            __builtin_amdgcn_s_setprio(1);
#pragma unroll
            for (int s = 0; s < 4; ++s) {
                const int rk = kb * 32 + q; const int cc = ((2 * s + h) ^ (rk & 7)) * 8;
                const f16x8 ah = *(f16x8*)&KB[kg][buf][rk][cc];
                c[kb] = __builtin_amdgcn_mfma_f32_32x32x16_f16(ah, qbh[s], c[kb], 0, 0, 0);
                c[kb] = __builtin_amdgcn_mfma_f32_32x32x16_f16(ah, qbl[s], c[kb], 0, 0, 0);
            }
            __builtin_amdgcn_s_setprio(0);
        }
    };

    // ---- pass 1: partial l over my K-half ----
    float lsum = 0.f;
    stageK(0, jb);
    for (int it = 0; it < HTIL; ++it) {
        __syncthreads();
        if (it + 1 < HTIL) stageK((it + 1) & 1, jb + it + 1);
        f32x16 c[2];
        qkt(it & 1, c);
#pragma unroll
        for (int kb = 0; kb < 2; ++kb)
#pragma unroll
            for (int r = 0; r < 16; ++r) lsum += __expf(c[kb][r]);
    }
    lsum += __shfl_xor(lsum, 32);

    float* ls = (float*)VB;
    if (h == 0) ls[w * 32 + q] = lsum;
    __syncthreads();
    const float linv = 1.f / (ls[qsub * 32 + q] + ls[(qsub + 4) * 32 + q]);
    __syncthreads();

    // ---- pass 2: my K-half — recompute s, write attn, partial PV ----
    f32x16 x0, x1;
#pragma unroll
    for (int r = 0; r < 16; ++r) { x0[r] = 0.f; x1[r] = 0.f; }

    stageK(0, jb);
    stageV(0, jb);
    for (int it = 0; it < HTIL; ++it) {
        const int j0 = (jb + it) * 64;
        __syncthreads();
        const int cur = it & 1;
        if (it + 1 < HTIL) { stageK(cur ^ 1, jb + it + 1); stageV(cur ^ 1, jb + it + 1); }

        f32x16 c[2];
        qkt(cur, c);

#pragma unroll
        for (int kb = 0; kb < 2; ++kb) {
            float p[16];
#pragma unroll
            for (int r = 0; r < 16; ++r) p[r] = __expf(c[kb][r]) * linv;

            const int kbase = j0 + kb * 32;
#pragma unroll
            for (int i = 0; i < 4; ++i) {
                f32x4 st;
                st[0] = p[4 * i]; st[1] = p[4 * i + 1]; st[2] = p[4 * i + 2]; st[3] = p[4 * i + 3];
                *(f32x4*)(attn + ((size_t)hh * NTOK + qrow) * NTOK + kbase + 8 * i + 4 * h) = st;
            }

            _Float16 hf[16];
#pragma unroll
            for (int r = 0; r < 16; ++r) hf[r] = (_Float16)p[r];
            unsigned ph[8];
#pragma unroll
            for (int i = 0; i < 8; ++i) ph[i] = packh(hf[2 * i], hf[2 * i + 1]);

#pragma unroll
            for (int ss = 0; ss < 2; ++ss) {
                const int b = 4 * ss;
                const unsigned eh0 = __shfl_xor(h ? ph[b + 0] : ph[b + 2], 32);
                const unsigned eh1 = __shfl_xor(h ? ph[b + 1] : ph[b + 3], 32);
                U8 pah;
                pah.u[0] = h ? eh0 : ph[b + 0]; pah.u[1] = h ? eh1 : ph[b + 1];
                pah.u[2] = h ? ph[b + 2] : eh0; pah.u[3] = h ? ph[b + 3] : eh1;
                const int ks = kb * 2 + ss;
                __builtin_amdgcn_s_setprio(1);
                {
                    const int rd0 = q; const int cv0 = ((2 * ks + h) ^ (rd0 & 7)) * 8;
                    const f16x8 vh = *(f16x8*)&VB[kg][cur][rd0][cv0];
                    x0 = __builtin_amdgcn_mfma_f32_32x32x16_f16(pah.v, vh, x0, 0, 0, 0);
                }
                {
                    const int rd1 = 32 + q; const int cv1 = ((2 * ks + h) ^ (rd1 & 7)) * 8;
                    const f16x8 vh = *(f16x8*)&VB[kg][cur][rd1][cv1];
                    x1 = __builtin_amdgcn_mfma_f32_32x32x16_f16(pah.v, vh, x1, 0, 0, 0);
                }
                __builtin_amdgcn_s_setprio(0);
            }
        }
    }

    __syncthreads();
    float* xs = (float*)KB;
    if (kg == 1) {
#pragma unroll
        for (int r = 0; r < 16; ++r) {
            xs[((qsub * 64) + l) * 32 + r]      = x0[r];
            xs[((qsub * 64) + l) * 32 + 16 + r] = x1[r];
        }
    }
    __syncthreads();
    if (kg == 0) {
#pragma unroll
        for (int r = 0; r < 16; ++r) {
            x0[r] += xs[((qsub * 64) + l) * 32 + r];
            x1[r] += xs[((qsub * 64) + l) * 32 + 16 + r];
        }
#pragma unroll
        for (int r = 0; r < 16; ++r) {
            const int qloc = (r & 3) + 8 * (r >> 2) + 4 * h;
            Xp[(size_t)(rw + qloc) * DMODEL + hh * DHEAD + q]      = x0[r];
            Xp[(size_t)(rw + qloc) * DMODEL + hh * DHEAD + 32 + q] = x1[r];
        }
    }
}

// ---------- output projection: A reg-staged (f32 split), B via global_load_lds ----------
__global__ void __launch_bounds__(256) out_mfma_kernel(
        const float* __restrict__ Xp,
        const _Float16* __restrict__ WH, const _Float16* __restrict__ WL,
        const float* __restrict__ bo, float* __restrict__ out) {
    __shared__ _Float16 Ah[64][40], Al[64][40], Bh[128][32], Bl[128][32];
    const int t = threadIdx.x;
    const int l = t & 63, wid = t >> 6;
    const int lr = l & 15, lk = l >> 4;
    const int m0 = blockIdx.y * 64, n0 = blockIdx.x * 128;
    const int wm = (wid >> 1) * 32, wn = (wid & 1) * 64;
    const char* BhB = (const char*)&Bh[0][0];
    const char* BlB = (const char*)&Bl[0][0];

    f32x4 acc[2][4];
#pragma unroll
    for (int mi = 0; mi < 2; ++mi)
#pragma unroll
        for (int ni = 0; ni < 4; ++ni)
#pragma unroll
            for (int e = 0; e < 4; ++e) acc[mi][ni][e] = 0.f;

    for (int k0 = 0; k0 < DMODEL; k0 += 32) {
        __syncthreads();
        // B planes via DMA (rotation-swizzled source)
#pragma unroll
        for (int p = 0; p < 2; ++p) {
            const int slot = p * 256 + t;
            const int rb = slot >> 2, sub = slot & 3;
            const int eub = (sub + 4 - ((rb >> 1) & 3)) & 3;
            char* dstH = (char*)&Bh[0][0] + p * 4096 + wid * 1024;
            char* dstL = (char*)&Bl[0][0] + p * 4096 + wid * 1024;
            GLD16(WH + (size_t)(n0 + rb) * DMODEL + k0 + eub * 8, dstH);
            GLD16(WL + (size_t)(n0 + rb) * DMODEL + k0 + eub * 8, dstL);
        }
        // A: f32 load + split (padded layout, unchanged)
#pragma unroll
        for (int p = 0; p < 2; ++p) {
            const int idx = t + p * 256;
            const int r = idx >> 3, c4 = (idx & 7) * 4;
            const size_t off = (size_t)(m0 + r) * DMODEL + k0 + c4;
            const float4 v0 = *(const float4*)(Xp + off);
            f16x4 hv, lv; _Float16 h, lo;
            split16(v0.x, h, lo); hv[0] = h; lv[0] = lo;
            split16(v0.y, h, lo); hv[1] = h; lv[1] = lo;
            split16(v0.z, h, lo); hv[2] = h; lv[2] = lo;
            split16(v0.w, h, lo); hv[3] = h; lv[3] = lo;
            *(f16x4*)&Ah[r][c4] = hv;
            *(f16x4*)&Al[r][c4] = lv;
        }
        __syncthreads();

        f16x8 ah[2], al[2], bh[4], bl[4];
#pragma unroll
        for (int i = 0; i < 2; ++i) {
            ah[i] = *(f16x8*)&Ah[wm + i * 16 + lr][lk * 8];
            al[i] = *(f16x8*)&Al[wm + i * 16 + lr][lk * 8];
        }
#pragma unroll
        for (int i = 0; i < 4; ++i) {
            const int row = wn + i * 16 + lr;
            const int off = row * 64 + (((lk + (row >> 1)) & 3) * 16);
            bh[i] = *(const f16x8*)(BhB + off);
            bl[i] = *(const f16x8*)(BlB + off);
        }
        __builtin_amdgcn_s_setprio(1);
#pragma unroll
        for (int mi = 0; mi < 2; ++mi)
#pragma unroll
            for (int ni = 0; ni < 4; ++ni) {
                acc[mi][ni] = __builtin_amdgcn_mfma_f32_16x16x32_f16(ah[mi], bh[ni], acc[mi][ni], 0, 0, 0);
                acc[mi][ni] = __builtin_amdgcn_mfma_f32_16x16x32_f16(ah[mi], bl[ni], acc[mi][ni], 0, 0, 0);
                acc[mi][ni] = __builtin_amdgcn_mfma_f32_16x16x32_f16(al[mi], bh[ni], acc[mi][ni], 0, 0, 0);
            }
        __builtin_amdgcn_s_setprio(0);
    }

#pragma unroll
    for (int ni = 0; ni < 4; ++ni) {
        const int col = n0 + wn + ni * 16 + lr;
        const float bv_ = bo[col];
#pragma unroll
        for (int mi = 0; mi < 2; ++mi)
#pragma unroll
            for (int i = 0; i < 4; ++i) {
                const int row = m0 + wm + mi * 16 + lk * 4 + i;
                out[(size_t)row * DMODEL + col] = acc[mi][ni][i] + bv_;
            }
    }
}

extern "C" void kernel_launch(void* const* d_in, const int* in_sizes, int n_in,
                              void* d_out, int out_size, void* d_ws, size_t ws_size,
                              hipStream_t stream) {
    (void)in_sizes; (void)n_in; (void)out_size; (void)ws_size;
    const float* query = (const float*)d_in[0];
    const float* key_  = (const float*)d_in[1];
    const float* value = (const float*)d_in[2];
    const float* Wq = (const float*)d_in[3];
    const float* bq = (const float*)d_in[4];
    const float* Wk = (const float*)d_in[5];
    const float* bk = (const float*)d_in[6];
    const float* Wv = (const float*)d_in[7];
    const float* bv = (const float*)d_in[8];
    const float* Wo = (const float*)d_in[9];
    const float* bo = (const float*)d_in[10];

    float* out  = (float*)d_out;
    float* attn = out + (size_t)NTOK * DMODEL;

    const size_t MM = (size_t)1024 * 1024;
    _Float16* ws16 = (_Float16*)d_ws;          // 32 MB used
    _Float16* Wt  = ws16;                      // 8 planes (Wq,Wk,Wv,Wo x hi/lo), 16 MB
    _Float16* Qh  = ws16 + 8 * MM;             // 4 x 4 MB planes
    _Float16* Ql  = Qh  + 2 * MM;
    _Float16* Kh_ = Ql  + 2 * MM;
    _Float16* Vth = Kh_ + 2 * MM;

    // dead-after-qkv alias: Xp (8 MB) over Wq/Wk hi planes
    float* Xp = (float*)ws16;

    // A-split scratch lives in the attn output region (dead until fused_attn rewrites it)
    _Float16* As = (_Float16*)attn;            // 12 MB of 268 MB

    dim3 blk(256);
    prep_w_kernel<<<dim3(32, 32, 4), blk, 0, stream>>>(Wq, Wk, Wv, Wo, Wt);
    prep_a_kernel<<<dim3(1024, 3), blk, 0, stream>>>(query, key_, value, As);
    qkv_mfma_kernel<<<dim3(8, 32, 3), blk, 0, stream>>>(As, Wt, bq, bk, bv,
                                                        Qh, Ql, Kh_, Vth);
    fused_attn_kernel<<<dim3(16, 16), dim3(512), 0, stream>>>(Qh, Ql, Kh_, Vth, attn, Xp);
    out_mfma_kernel<<<dim3(8, 32), blk, 0, stream>>>(Xp, Wt + 6 * MM, Wt + 7 * MM, bo, out);
}

// Round 19
// 204.237 us; speedup vs baseline: 1.1404x; 1.0477x over previous
//
#include <hip/hip_runtime.h>
#include <math.h>

#define NTOK 2048
#define DMODEL 1024
#define NHEAD 16
#define DHEAD 64
#define NTIL (NTOK / 64)   // 32 K-tiles total
#define HTIL (NTIL / 2)    // 16 per K-half group

typedef _Float16 f16x8 __attribute__((ext_vector_type(8)));
typedef _Float16 f16x4 __attribute__((ext_vector_type(4)));
typedef _Float16 f16x2 __attribute__((ext_vector_type(2)));
typedef float f32x4 __attribute__((ext_vector_type(4)));
typedef float f32x16 __attribute__((ext_vector_type(16)));

union U32H2 { f16x2 h; unsigned u; };
union U8 { f16x8 v; unsigned u[4]; };

__device__ __forceinline__ void split16(float x, _Float16& hi, _Float16& lo) {
    hi = (_Float16)x;
    lo = (_Float16)(x - (float)hi);
}
__device__ __forceinline__ unsigned packh(_Float16 a, _Float16 b) {
    U32H2 c; c.h = f16x2{a, b}; return c.u;
}

#define GLD16(gsrc, ldst)                                                             \
    __builtin_amdgcn_global_load_lds(                                                 \
        (const __attribute__((address_space(1))) void*)(gsrc),                        \
        (__attribute__((address_space(3))) void*)(ldst), 16, 0, 0)

// ---------- prep: W[k][n] f32 -> Wt_hi/Wt_lo [n][k] f16, 4 matrices ----------
__global__ void __launch_bounds__(256) prep_w_kernel(
        const float* __restrict__ Wq, const float* __restrict__ Wk,
        const float* __restrict__ Wv, const float* __restrict__ Wo,
        _Float16* __restrict__ Wt) {
    __shared__ float T[32][33];
    const int z = blockIdx.z;
    const float* W = (z == 0) ? Wq : (z == 1) ? Wk : (z == 2) ? Wv : Wo;
    _Float16* Whi = Wt + (size_t)z * 2 * 1024 * 1024;
    _Float16* Wlo = Whi + (size_t)1024 * 1024;
    const int t = threadIdx.x;
    const int k0 = blockIdx.y * 32, n0 = blockIdx.x * 32;
    const int r = t >> 3, c4 = (t & 7) * 4;
    const float4 v = *(const float4*)(W + (size_t)(k0 + r) * DMODEL + n0 + c4);
    T[r][c4 + 0] = v.x; T[r][c4 + 1] = v.y; T[r][c4 + 2] = v.z; T[r][c4 + 3] = v.w;
    __syncthreads();
    f16x4 hv, lv;
#pragma unroll
    for (int j = 0; j < 4; ++j) {
        _Float16 h, l;
        split16(T[c4 + j][r], h, l);
        hv[j] = h; lv[j] = l;
    }
    *(f16x4*)(Whi + (size_t)(n0 + r) * DMODEL + k0 + c4) = hv;
    *(f16x4*)(Wlo + (size_t)(n0 + r) * DMODEL + k0 + c4) = lv;
}

// ---------- QKV projection: A f32 in-kernel split (reg-staged), B via global_load_lds ----------
// Outputs: z=0 -> Qh+Ql (x0.125); z=1 -> Kh only; z=2 -> Vth only.
__global__ void __launch_bounds__(256) qkv_mfma_kernel(
        const float* __restrict__ Aq, const float* __restrict__ Ak, const float* __restrict__ Av,
        const _Float16* __restrict__ Wt,
        const float* __restrict__ bq, const float* __restrict__ bk, const float* __restrict__ bv,
        _Float16* __restrict__ Qh, _Float16* __restrict__ Ql,
        _Float16* __restrict__ Kh, _Float16* __restrict__ Vth) {
    __shared__ _Float16 Ah[64][32], Al[64][32], Bh[128][32], Bl[128][32];
    const int z = blockIdx.z;
    const float* A = (z == 0) ? Aq : (z == 1) ? Ak : Av;
    const _Float16* WH = Wt + (size_t)z * 2 * 1024 * 1024;
    const _Float16* WL = WH + (size_t)1024 * 1024;
    const float* bias = (z == 0) ? bq : (z == 1) ? bk : bv;

    const int t = threadIdx.x;
    const int l = t & 63, wid = t >> 6;
    const int lr = l & 15, lk = l >> 4;
    const int m0 = blockIdx.y * 64, n0 = blockIdx.x * 128;
    const int wm = (wid >> 1) * 32, wn = (wid & 1) * 64;

    // A staging: thread t owns row rA = t>>2, global col-unit euA = t&3 (8 f32)
    const int rA = t >> 2, euA = t & 3;
    const int suA = (euA + (rA >> 1)) & 3;           // rotation-swizzled LDS slot unit
    const int aOffB = rA * 64 + suA * 16;            // byte offset in plane
    const char* AhB = (const char*)&Ah[0][0];
    const char* AlB = (const char*)&Al[0][0];
    const char* BhB = (const char*)&Bh[0][0];
    const char* BlB = (const char*)&Bl[0][0];

    f32x4 acc[2][4];
#pragma unroll
    for (int mi = 0; mi < 2; ++mi)
#pragma unroll
        for (int ni = 0; ni < 4; ++ni)
#pragma unroll
            for (int e = 0; e < 4; ++e) acc[mi][ni][e] = 0.f;

    for (int k0 = 0; k0 < DMODEL; k0 += 32) {
        __syncthreads();
        // B planes via DMA (rotation-swizzled source), 2 x 16B per thread per plane
#pragma unroll
        for (int p = 0; p < 2; ++p) {
            const int slot = p * 256 + t;
            const int rb = slot >> 2, sub = slot & 3;
            const int eub = (sub + 4 - ((rb >> 1) & 3)) & 3;
            char* dstH = (char*)&Bh[0][0] + p * 4096 + wid * 1024;
            char* dstL = (char*)&Bl[0][0] + p * 4096 + wid * 1024;
            GLD16(WH + (size_t)(n0 + rb) * DMODEL + k0 + eub * 8, dstH);
            GLD16(WL + (size_t)(n0 + rb) * DMODEL + k0 + eub * 8, dstL);
        }
        // A: f32 load + in-kernel split -> swizzled LDS (one b128 store per plane)
        {
            const size_t off = (size_t)(m0 + rA) * DMODEL + k0 + euA * 8;
            const float4 a = *(const float4*)(A + off);
            const float4 b = *(const float4*)(A + off + 4);
            f16x8 hv, lv; _Float16 h, lo;
            split16(a.x, h, lo); hv[0] = h; lv[0] = lo;
            split16(a.y, h, lo); hv[1] = h; lv[1] = lo;
            split16(a.z, h, lo); hv[2] = h; lv[2] = lo;
            split16(a.w, h, lo); hv[3] = h; lv[3] = lo;
            split16(b.x, h, lo); hv[4] = h; lv[4] = lo;
            split16(b.y, h, lo); hv[5] = h; lv[5] = lo;
            split16(b.z, h, lo); hv[6] = h; lv[6] = lo;
            split16(b.w, h, lo); hv[7] = h; lv[7] = lo;
            *(f16x8*)((char*)&Ah[0][0] + aOffB) = hv;
            *(f16x8*)((char*)&Al[0][0] + aOffB) = lv;
        }
        __syncthreads();

        f16x8 ah[2], al[2], bh[4], bl[4];
#pragma unroll
        for (int i = 0; i < 2; ++i) {
            const int row = wm + i * 16 + lr;
            const int off = row * 64 + (((lk + (row >> 1)) & 3) * 16);
            ah[i] = *(const f16x8*)(AhB + off);
            al[i] = *(const f16x8*)(AlB + off);
        }
#pragma unroll
        for (int i = 0; i < 4; ++i) {
            const int row = wn + i * 16 + lr;
            const int off = row * 64 + (((lk + (row >> 1)) & 3) * 16);
            bh[i] = *(const f16x8*)(BhB + off);
            bl[i] = *(const f16x8*)(BlB + off);
        }
        __builtin_amdgcn_s_setprio(1);
#pragma unroll
        for (int mi = 0; mi < 2; ++mi)
#pragma unroll
            for (int ni = 0; ni < 4; ++ni) {
                acc[mi][ni] = __builtin_amdgcn_mfma_f32_16x16x32_f16(ah[mi], bh[ni], acc[mi][ni], 0, 0, 0);
                acc[mi][ni] = __builtin_amdgcn_mfma_f32_16x16x32_f16(ah[mi], bl[ni], acc[mi][ni], 0, 0, 0);
                acc[mi][ni] = __builtin_amdgcn_mfma_f32_16x16x32_f16(al[mi], bh[ni], acc[mi][ni], 0, 0, 0);
            }
        __builtin_amdgcn_s_setprio(0);
    }

#pragma unroll
    for (int ni = 0; ni < 4; ++ni) {
        const int col = n0 + wn + ni * 16 + lr;
        const float bv_ = bias[col];
#pragma unroll
        for (int mi = 0; mi < 2; ++mi) {
            if (z == 2) {
                f16x4 hv;
#pragma unroll
                for (int i = 0; i < 4; ++i) hv[i] = (_Float16)(acc[mi][ni][i] + bv_);
                const int row = m0 + wm + mi * 16 + lk * 4;
                *(f16x4*)(Vth + (size_t)col * NTOK + row) = hv;
            } else {
#pragma unroll
                for (int i = 0; i < 4; ++i) {
                    const int row = m0 + wm + mi * 16 + lk * 4 + i;
                    float v = acc[mi][ni][i] + bv_;
                    if (z == 0) {
                        v *= 0.125f;
                        _Float16 h, lo;
                        split16(v, h, lo);
                        Qh[(size_t)row * DMODEL + col] = h;
                        Ql[(size_t)row * DMODEL + col] = lo;
                    } else {
                        Kh[(size_t)row * DMODEL + col] = (_Float16)v;
                    }
                }
            }
        }
    }
}

// ---------- fused attention: 512 threads = 4 q-subblocks x 2 K-half groups (R17) ----------
__global__ void __launch_bounds__(512, 2) fused_attn_kernel(
        const _Float16* __restrict__ Qh, const _Float16* __restrict__ Ql,
        const _Float16* __restrict__ Kh, const _Float16* __restrict__ Vth,
        float* __restrict__ attn, float* __restrict__ Xp) {
    __shared__ _Float16 KB[2][2][64][64];
    __shared__ _Float16 VB[2][2][64][64];
    const int t = threadIdx.x, l = t & 63, w = t >> 6, q = l & 31, h = l >> 5;
    const int qsub = w & 3, kg = w >> 2;
    const int hh = blockIdx.y;
    const int rw = blockIdx.x * 128 + qsub * 32;
    const int tg = t & 255;
    const int sr = tg >> 3, sc = tg & 7;
    const int qrow = rw + q;
    const int jb = kg * HTIL;

    f16x8 qbh[4], qbl[4];
#pragma unroll
    for (int s = 0; s < 4; ++s) {
        const size_t off = (size_t)qrow * DMODEL + hh * DHEAD + s * 16 + h * 8;
        qbh[s] = *(const f16x8*)(Qh + off);
        qbl[s] = *(const f16x8*)(Ql + off);
    }

    auto stageK = [&](int buf, int tile) {
        const int j0 = tile * 64;
#pragma unroll
        for (int p = 0; p < 2; ++p) {
            const int r = sr + p * 32; const int cs = (sc ^ (r & 7)) * 8;
            *(f16x8*)&KB[kg][buf][r][cs] = *(const f16x8*)(Kh + (size_t)(j0 + r) * DMODEL + hh * DHEAD + sc * 8);
        }
    };
    auto stageV = [&](int buf, int tile) {
        const int j0 = tile * 64;
#pragma unroll
        for (int p = 0; p < 2; ++p) {
            const int r = sr + p * 32; const int cs = (sc ^ (r & 7)) * 8;
            *(f16x8*)&VB[kg][buf][r][cs] = *(const f16x8*)(Vth + (size_t)(hh * DHEAD + r) * NTOK + j0 + sc * 8);
        }
    };
    auto qkt = [&](int buf, f32x16 (&c)[2]) {
#pragma unroll
        for (int kb = 0; kb < 2; ++kb) {
#pragma unroll
            for (int r = 0; r < 16; ++r) c[kb][r] = 0.f;
            __builtin_amdgcn_s_setprio(1);
#pragma unroll
            for (int s = 0; s < 4; ++s) {
                const int rk = kb * 32 + q; const int cc = ((2 * s + h) ^ (rk & 7)) * 8;
                const f16x8 ah = *(f16x8*)&KB[kg][buf][rk][cc];
                c[kb] = __builtin_amdgcn_mfma_f32_32x32x16_f16(ah, qbh[s], c[kb], 0, 0, 0);
                c[kb] = __builtin_amdgcn_mfma_f32_32x32x16_f16(ah, qbl[s], c[kb], 0, 0, 0);
            }
            __builtin_amdgcn_s_setprio(0);
        }
    };

    // ---- pass 1: partial l over my K-half ----
    float lsum = 0.f;
    stageK(0, jb);
    for (int it = 0; it < HTIL; ++it) {
        __syncthreads();
        if (it + 1 < HTIL) stageK((it + 1) & 1, jb + it + 1);
        f32x16 c[2];
        qkt(it & 1, c);
#pragma unroll
        for (int kb = 0; kb < 2; ++kb)
#pragma unroll
            for (int r = 0; r < 16; ++r) lsum += __expf(c[kb][r]);
    }
    lsum += __shfl_xor(lsum, 32);

    float* ls = (float*)VB;
    if (h == 0) ls[w * 32 + q] = lsum;
    __syncthreads();
    const float linv = 1.f / (ls[qsub * 32 + q] + ls[(qsub + 4) * 32 + q]);
    __syncthreads();

    // ---- pass 2: my K-half — recompute s, write attn, partial PV ----
    f32x16 x0, x1;
#pragma unroll
    for (int r = 0; r < 16; ++r) { x0[r] = 0.f; x1[r] = 0.f; }

    stageK(0, jb);
    stageV(0, jb);
    for (int it = 0; it < HTIL; ++it) {
        const int j0 = (jb + it) * 64;
        __syncthreads();
        const int cur = it & 1;
        if (it + 1 < HTIL) { stageK(cur ^ 1, jb + it + 1); stageV(cur ^ 1, jb + it + 1); }

        f32x16 c[2];
        qkt(cur, c);

#pragma unroll
        for (int kb = 0; kb < 2; ++kb) {
            float p[16];
#pragma unroll
            for (int r = 0; r < 16; ++r) p[r] = __expf(c[kb][r]) * linv;

            const int kbase = j0 + kb * 32;
#pragma unroll
            for (int i = 0; i < 4; ++i) {
                f32x4 st;
                st[0] = p[4 * i]; st[1] = p[4 * i + 1]; st[2] = p[4 * i + 2]; st[3] = p[4 * i + 3];
                *(f32x4*)(attn + ((size_t)hh * NTOK + qrow) * NTOK + kbase + 8 * i + 4 * h) = st;
            }

            _Float16 hf[16];
#pragma unroll
            for (int r = 0; r < 16; ++r) hf[r] = (_Float16)p[r];
            unsigned ph[8];
#pragma unroll
            for (int i = 0; i < 8; ++i) ph[i] = packh(hf[2 * i], hf[2 * i + 1]);

#pragma unroll
            for (int ss = 0; ss < 2; ++ss) {
                const int b = 4 * ss;
                const unsigned eh0 = __shfl_xor(h ? ph[b + 0] : ph[b + 2], 32);
                const unsigned eh1 = __shfl_xor(h ? ph[b + 1] : ph[b + 3], 32);
                U8 pah;
                pah.u[0] = h ? eh0 : ph[b + 0]; pah.u[1] = h ? eh1 : ph[b + 1];
                pah.u[2] = h ? ph[b + 2] : eh0; pah.u[3] = h ? ph[b + 3] : eh1;
                const int ks = kb * 2 + ss;
                __builtin_amdgcn_s_setprio(1);
                {
                    const int rd0 = q; const int cv0 = ((2 * ks + h) ^ (rd0 & 7)) * 8;
                    const f16x8 vh = *(f16x8*)&VB[kg][cur][rd0][cv0];
                    x0 = __builtin_amdgcn_mfma_f32_32x32x16_f16(pah.v, vh, x0, 0, 0, 0);
                }
                {
                    const int rd1 = 32 + q; const int cv1 = ((2 * ks + h) ^ (rd1 & 7)) * 8;
                    const f16x8 vh = *(f16x8*)&VB[kg][cur][rd1][cv1];
                    x1 = __builtin_amdgcn_mfma_f32_32x32x16_f16(pah.v, vh, x1, 0, 0, 0);
                }
                __builtin_amdgcn_s_setprio(0);
            }
        }
    }

    __syncthreads();
    float* xs = (float*)KB;
    if (kg == 1) {
#pragma unroll
        for (int r = 0; r < 16; ++r) {
            xs[((qsub * 64) + l) * 32 + r]      = x0[r];
            xs[((qsub * 64) + l) * 32 + 16 + r] = x1[r];
        }
    }
    __syncthreads();
    if (kg == 0) {
#pragma unroll
        for (int r = 0; r < 16; ++r) {
            x0[r] += xs[((qsub * 64) + l) * 32 + r];
            x1[r] += xs[((qsub * 64) + l) * 32 + 16 + r];
        }
#pragma unroll
        for (int r = 0; r < 16; ++r) {
            const int qloc = (r & 3) + 8 * (r >> 2) + 4 * h;
            Xp[(size_t)(rw + qloc) * DMODEL + hh * DHEAD + q]      = x0[r];
            Xp[(size_t)(rw + qloc) * DMODEL + hh * DHEAD + 32 + q] = x1[r];
        }
    }
}

// ---------- output projection: A reg-staged (f32 split), B via global_load_lds ----------
__global__ void __launch_bounds__(256) out_mfma_kernel(
        const float* __restrict__ Xp,
        const _Float16* __restrict__ WH, const _Float16* __restrict__ WL,
        const float* __restrict__ bo, float* __restrict__ out) {
    __shared__ _Float16 Ah[64][40], Al[64][40], Bh[128][32], Bl[128][32];
    const int t = threadIdx.x;
    const int l = t & 63, wid = t >> 6;
    const int lr = l & 15, lk = l >> 4;
    const int m0 = blockIdx.y * 64, n0 = blockIdx.x * 128;
    const int wm = (wid >> 1) * 32, wn = (wid & 1) * 64;
    const char* BhB = (const char*)&Bh[0][0];
    const char* BlB = (const char*)&Bl[0][0];

    f32x4 acc[2][4];
#pragma unroll
    for (int mi = 0; mi < 2; ++mi)
#pragma unroll
        for (int ni = 0; ni < 4; ++ni)
#pragma unroll
            for (int e = 0; e < 4; ++e) acc[mi][ni][e] = 0.f;

    for (int k0 = 0; k0 < DMODEL; k0 += 32) {
        __syncthreads();
#pragma unroll
        for (int p = 0; p < 2; ++p) {
            const int slot = p * 256 + t;
            const int rb = slot >> 2, sub = slot & 3;
            const int eub = (sub + 4 - ((rb >> 1) & 3)) & 3;
            char* dstH = (char*)&Bh[0][0] + p * 4096 + wid * 1024;
            char* dstL = (char*)&Bl[0][0] + p * 4096 + wid * 1024;
            GLD16(WH + (size_t)(n0 + rb) * DMODEL + k0 + eub * 8, dstH);
            GLD16(WL + (size_t)(n0 + rb) * DMODEL + k0 + eub * 8, dstL);
        }
#pragma unroll
        for (int p = 0; p < 2; ++p) {
            const int idx = t + p * 256;
            const int r = idx >> 3, c4 = (idx & 7) * 4;
            const size_t off = (size_t)(m0 + r) * DMODEL + k0 + c4;
            const float4 v0 = *(const float4*)(Xp + off);
            f16x4 hv, lv; _Float16 h, lo;
            split16(v0.x, h, lo); hv[0] = h; lv[0] = lo;
            split16(v0.y, h, lo); hv[1] = h; lv[1] = lo;
            split16(v0.z, h, lo); hv[2] = h; lv[2] = lo;
            split16(v0.w, h, lo); hv[3] = h; lv[3] = lo;
            *(f16x4*)&Ah[r][c4] = hv;
            *(f16x4*)&Al[r][c4] = lv;
        }
        __syncthreads();

        f16x8 ah[2], al[2], bh[4], bl[4];
#pragma unroll
        for (int i = 0; i < 2; ++i) {
            ah[i] = *(f16x8*)&Ah[wm + i * 16 + lr][lk * 8];
            al[i] = *(f16x8*)&Al[wm + i * 16 + lr][lk * 8];
        }
#pragma unroll
        for (int i = 0; i < 4; ++i) {
            const int row = wn + i * 16 + lr;
            const int off = row * 64 + (((lk + (row >> 1)) & 3) * 16);
            bh[i] = *(const f16x8*)(BhB + off);
            bl[i] = *(const f16x8*)(BlB + off);
        }
        __builtin_amdgcn_s_setprio(1);
#pragma unroll
        for (int mi = 0; mi < 2; ++mi)
#pragma unroll
            for (int ni = 0; ni < 4; ++ni) {
                acc[mi][ni] = __builtin_amdgcn_mfma_f32_16x16x32_f16(ah[mi], bh[ni], acc[mi][ni], 0, 0, 0);
                acc[mi][ni] = __builtin_amdgcn_mfma_f32_16x16x32_f16(ah[mi], bl[ni], acc[mi][ni], 0, 0, 0);
                acc[mi][ni] = __builtin_amdgcn_mfma_f32_16x16x32_f16(al[mi], bh[ni], acc[mi][ni], 0, 0, 0);
            }
        __builtin_amdgcn_s_setprio(0);
    }

#pragma unroll
    for (int ni = 0; ni < 4; ++ni) {
        const int col = n0 + wn + ni * 16 + lr;
        const float bv_ = bo[col];
#pragma unroll
        for (int mi = 0; mi < 2; ++mi)
#pragma unroll
            for (int i = 0; i < 4; ++i) {
                const int row = m0 + wm + mi * 16 + lk * 4 + i;
                out[(size_t)row * DMODEL + col] = acc[mi][ni][i] + bv_;
            }
    }
}

extern "C" void kernel_launch(void* const* d_in, const int* in_sizes, int n_in,
                              void* d_out, int out_size, void* d_ws, size_t ws_size,
                              hipStream_t stream) {
    (void)in_sizes; (void)n_in; (void)out_size; (void)ws_size;
    const float* query = (const float*)d_in[0];
    const float* key_  = (const float*)d_in[1];
    const float* value = (const float*)d_in[2];
    const float* Wq = (const float*)d_in[3];
    const float* bq = (const float*)d_in[4];
    const float* Wk = (const float*)d_in[5];
    const float* bk = (const float*)d_in[6];
    const float* Wv = (const float*)d_in[7];
    const float* bv = (const float*)d_in[8];
    const float* Wo = (const float*)d_in[9];
    const float* bo = (const float*)d_in[10];

    float* out  = (float*)d_out;
    float* attn = out + (size_t)NTOK * DMODEL;

    const size_t MM = (size_t)1024 * 1024;
    _Float16* ws16 = (_Float16*)d_ws;          // 32 MB used
    _Float16* Wt  = ws16;                      // 8 planes (Wq,Wk,Wv,Wo x hi/lo), 16 MB
    _Float16* Qh  = ws16 + 8 * MM;             // 4 x 4 MB planes
    _Float16* Ql  = Qh  + 2 * MM;
    _Float16* Kh_ = Ql  + 2 * MM;
    _Float16* Vth = Kh_ + 2 * MM;

    // dead-after-qkv alias: Xp (8 MB) over Wq/Wk hi planes
    float* Xp = (float*)ws16;

    dim3 blk(256);
    prep_w_kernel<<<dim3(32, 32, 4), blk, 0, stream>>>(Wq, Wk, Wv, Wo, Wt);
    qkv_mfma_kernel<<<dim3(8, 32, 3), blk, 0, stream>>>(query, key_, value, Wt, bq, bk, bv,
                                                        Qh, Ql, Kh_, Vth);
    fused_attn_kernel<<<dim3(16, 16), dim3(512), 0, stream>>>(Qh, Ql, Kh_, Vth, attn, Xp);
    out_mfma_kernel<<<dim3(8, 32), blk, 0, stream>>>(Xp, Wt + 6 * MM, Wt + 7 * MM, bo, out);
}